// Round 19
// baseline (348.271 us; speedup 1.0000x reference)
//
#include <hip/hip_runtime.h>

#define N_GRAPHS_C 1000
#define NPG_C      100
#define N_EDGES_C  3200000
#define KTOP_C     30
#define CAP        4096      // per-graph edge-slot capacity (mean 3200, sigma ~57)
#define NB_BUCKET  391       // edge blocks; block NB_BUCKET does wprep
#define NB_MAIN    768       // persistent main blocks (256 CU x 3 blocks/CU)
#define EXTRA_G    (N_GRAPHS_C - NB_MAIN)   // 232 blocks take a 2nd graph

typedef _Float16 f16x8 __attribute__((ext_vector_type(8)));
typedef float    f32x4 __attribute__((ext_vector_type(4)));

__device__ __forceinline__ unsigned packh2(float x, float y) {
    _Float16 hx = (_Float16)x, hy = (_Float16)y;
    return (unsigned)__builtin_bit_cast(unsigned short, hx) |
           ((unsigned)__builtin_bit_cast(unsigned short, hy) << 16);
}

__device__ __forceinline__ float f16b(unsigned v) {
    return (float)__builtin_bit_cast(_Float16, (unsigned short)v);
}

__device__ __forceinline__ float ftanh(float x) {
    float e = __expf(2.0f * x);
    return 1.0f - 2.0f * __builtin_amdgcn_rcpf(e + 1.0f);
}

__device__ __forceinline__ void split8(const float* v, f16x8& h, f16x8& l) {
    #pragma unroll
    for (int j = 0; j < 8; ++j) {
        _Float16 hh = (_Float16)v[j];
        h[j] = hh;
        l[j] = (_Float16)(v[j] - (float)hh);
    }
}

// ---------------- workspace layout (bytes) ----------------
// [0, 4096)                 : gcur  int[1024]  (memset to 0)
// [4096, 8196096)           : slots u16[1000*4096]  packed edges (d<<7 | s)
// [8196096, +24576)         : wp — f16 hi/lo planes of W1/W2/W3 (6144 words)

__global__ __launch_bounds__(1024)
void bucket_kernel(const int* __restrict__ src, const int* __restrict__ dst,
                   int* __restrict__ gcur, unsigned short* __restrict__ slots,
                   const float* __restrict__ W1, const float* __restrict__ W2,
                   const float* __restrict__ W3, unsigned* __restrict__ wp) {
    const int tid = threadIdx.x;
    if (blockIdx.x == NB_BUCKET) {
        for (int w = tid; w < 2048; w += 1024) {
            int n = w >> 6, kp = w & 63, k = kp * 2;
            float a = W1[k*32 + n], b = W1[(k+1)*32 + n];
            _Float16 ah = (_Float16)a, bh = (_Float16)b;
            wp[w]        = (unsigned)__builtin_bit_cast(unsigned short, ah) |
                           ((unsigned)__builtin_bit_cast(unsigned short, bh) << 16);
            wp[2048 + w] = packh2(a - (float)ah, b - (float)bh);
        }
        for (int w = tid; w < 512; w += 1024) {
            int n = w >> 4, kp = w & 15, k = kp * 2;
            float a = W2[k*32 + n], b = W2[(k+1)*32 + n];
            _Float16 ah = (_Float16)a, bh = (_Float16)b;
            wp[4096 + w] = (unsigned)__builtin_bit_cast(unsigned short, ah) |
                           ((unsigned)__builtin_bit_cast(unsigned short, bh) << 16);
            wp[4608 + w] = packh2(a - (float)ah, b - (float)bh);
            float a3 = W3[k*32 + n], b3v = W3[(k+1)*32 + n];
            _Float16 a3h = (_Float16)a3, b3h = (_Float16)b3v;
            wp[5120 + w] = (unsigned)__builtin_bit_cast(unsigned short, a3h) |
                           ((unsigned)__builtin_bit_cast(unsigned short, b3h) << 16);
            wp[5632 + w] = packh2(a3 - (float)a3h, b3v - (float)b3h);
        }
        return;
    }

    __shared__ int hist[N_GRAPHS_C];
    const int base = blockIdx.x * 8192;
    for (int i = tid; i < N_GRAPHS_C; i += 1024) hist[i] = 0;
    __syncthreads();

    int g[8]; unsigned short pk[8]; bool v[8];
    #pragma unroll
    for (int k = 0; k < 8; ++k) {
        int e = base + tid + k * 1024;
        v[k] = false;
        if (e < N_EDGES_C) {
            int s = src[e], d = dst[e];
            if (s != d) {
                int gg = s / NPG_C;
                g[k] = gg;
                pk[k] = (unsigned short)(((d - gg * NPG_C) << 7) | (s - gg * NPG_C));
                v[k] = true;
                atomicAdd(&hist[gg], 1);
            }
        }
    }
    __syncthreads();
    for (int i = tid; i < N_GRAPHS_C; i += 1024) {
        int c = hist[i];
        hist[i] = atomicAdd(&gcur[i], c);
    }
    __syncthreads();
    #pragma unroll
    for (int k = 0; k < 8; ++k) {
        if (v[k]) {
            int pos = atomicAdd(&hist[g[k]], 1);
            if (pos < CAP) slots[g[k] * CAP + pos] = pk[k];
        }
    }
}

// ---------------- main persistent kernel: 768 blocks, 1-2 graphs each ----------------
// LDS (u32 word offsets), total 12848 words = 51,392 B -> 3 blocks/CU (r16 layout):
//  bufA [0,4352)  bufB [4352,8704)  xrows/pooled [8704,12304)
//  dis [12304,12416)  t4 [12416,12520)  t4h [12520,12584)  t4l [12584,12648)
//  sX4 [12648,12748)  srank [12748,12848)
//  tail bufs sPb/s6/sO1/sFc/sZ (1248 f32) alias bufA
#define SMEM_WORDS 12848

extern "C" __global__ __launch_bounds__(512, 6)
void dgcnn_kernel(const float* __restrict__ x,
                  const int* __restrict__ gcur, const unsigned short* __restrict__ slots,
                  const unsigned* __restrict__ wp,
                  const float* __restrict__ b1, const float* __restrict__ b2,
                  const float* __restrict__ b3,
                  const float* __restrict__ W4, const float* __restrict__ b4,
                  const float* __restrict__ w5, const float* __restrict__ b5,
                  const float* __restrict__ w6, const float* __restrict__ b6,
                  const float* __restrict__ fw1, const float* __restrict__ fb1,
                  const float* __restrict__ fw2, const float* __restrict__ fb2,
                  float* __restrict__ out)
{
    extern __shared__ unsigned smu[];
    unsigned* bufA = smu;                      // 4352
    unsigned* bufB = smu + 4352;               // 4352
    float* xrows  = (float*)(smu + 8704);      // 3600, stride 36
    float* pooled = (float*)(smu + 8704);      // [30][100] aliases xrows (dead)
    float* dis = (float*)(smu + 12304);        // 112
    float* t4  = (float*)(smu + 12416);        // 104
    unsigned* t4h = smu + 12520;               // 64
    unsigned* t4l = smu + 12584;               // 64
    float* sX4 = (float*)(smu + 12648);        // 100
    int*   srank = (int*)(smu + 12748);        // 100
    float* sPb = (float*)smu;                  // 240  (tail aliases bufA)
    float* s6  = (float*)smu + 240;            // 352
    float* sO1 = (float*)smu + 592;            // 128
    float* sFc = (float*)smu + 720;            // 512
    float* sZ  = (float*)smu + 1232;           // 16

    const int tid = threadIdx.x;
    const int l64 = tid & 63;
    const int wv  = tid >> 6;                  // 0..7
    const unsigned* w1h = wp;
    const unsigned* w1l = wp + 2048;

    // graph list for this block: own id, plus maybe one of the 232 extras
    const int b = blockIdx.x;
    const int e0 = (int)(((long)b * EXTRA_G) / NB_MAIN);
    const int e1 = (int)(((long)(b + 1) * EXTRA_G) / NB_MAIN);
    const int ngr = 1 + (e1 > e0);

    for (int rep = 0; rep < ngr; ++rep) {
        const int g = (rep == 0) ? b : (NB_MAIN + e0);
        const float* xg = x + (size_t)g * NPG_C * 128;
        __syncthreads();   // protect LDS reuse across iterations

        // ---- P0: zero scatter area; dis pads; rowsum accumulator ----
        for (int idx = tid; idx < 2600; idx += 512) bufA[idx] = 0u;
        if (tid < 12) dis[100 + tid] = 0.f;
        if (tid < 100) srank[tid] = 0;
        __syncthreads();

        // ---- P1: scatter u8 counts (u8[100][104], row stride 26 words) ----
        {
            int ec = gcur[g]; if (ec > CAP) ec = CAP;
            for (int k = tid; k < ec; k += 512) {
                unsigned e = slots[g * CAP + k];
                unsigned idx = (e >> 7) * 104 + (e & 127);
                atomicAdd(&bufA[idx >> 2], 1u << ((idx & 3) * 8));
            }
        }
        __syncthreads();

        // ---- P2: wave-parallel rowsums + cnt A-frags -> registers ----
        if (tid < 400) {
            int row = tid >> 2, part = tid & 3;
            int wb = part * 7, we = (part == 3) ? 26 : wb + 7;
            const unsigned* rw = bufA + row * 26;
            unsigned s = 0;
            for (int k = wb; k < we; ++k) {
                unsigned v = rw[k];
                s += (v & 0xffu) + ((v >> 8) & 0xffu) + ((v >> 16) & 0xffu) + (v >> 24);
            }
            atomicAdd(&srank[row], (int)s);
        }
        f16x8 afr[4];
        {
            const int arow = (wv << 4) + (l64 & 15);
            if (wv < 7 && arow < 100) {
                const unsigned* cb = bufA + arow * 26 + ((l64 >> 4) << 1);
                #pragma unroll
                for (int ks = 0; ks < 4; ++ks) {
                    uint2 cw = *(const uint2*)(cb + ks * 8);
                    #pragma unroll
                    for (int j = 0; j < 4; ++j) {
                        afr[ks][j]     = (_Float16)(float)((cw.x >> (8*j)) & 255u);
                        afr[ks][4 + j] = (_Float16)(float)((cw.y >> (8*j)) & 255u);
                    }
                }
            } else {
                #pragma unroll
                for (int ks = 0; ks < 4; ++ks)
                    #pragma unroll
                    for (int j = 0; j < 8; ++j) afr[ks][j] = (_Float16)0.f;
            }
        }
        __syncthreads();

        // ---- P3: dis = rsqrt(rowsum + 1) ----
        if (tid < 100) dis[tid] = rsqrtf((float)srank[tid] + 1.0f);
        __syncthreads();

        // ---- C-frag -> Td planes (target buffer) ----
        auto packStore = [&](unsigned* buf, f32x4 c, int n, int r0, float4 dv) {
            float v0 = c[0]*dv.x, v1 = c[1]*dv.y, v2 = c[2]*dv.z, v3 = c[3]*dv.w;
            _Float16 h0=(_Float16)v0, h1=(_Float16)v1, h2=(_Float16)v2, h3=(_Float16)v3;
            uint2 wh, wl;
            wh.x = (unsigned)__builtin_bit_cast(unsigned short,h0) |
                   ((unsigned)__builtin_bit_cast(unsigned short,h1) << 16);
            wh.y = (unsigned)__builtin_bit_cast(unsigned short,h2) |
                   ((unsigned)__builtin_bit_cast(unsigned short,h3) << 16);
            wl.x = packh2(v0-(float)h0, v1-(float)h1);
            wl.y = packh2(v2-(float)h2, v3-(float)h3);
            *(uint2*)&buf[n*68 + (r0>>1)] = wh;
            *(uint2*)&buf[2176 + n*68 + (r0>>1)] = wl;
        };

        // ---- P4: zero pad words in BOTH buffers; L1 = X@W1 MFMA -> bufA ----
        for (int idx = tid; idx < 1536; idx += 512) {
            int bsel = idx >> 9;
            int r = idx & 511;
            int rw = (bsel * 512 + r) / 12, wd = (bsel * 512 + r) % 12;
            if (rw < 64) bufA[rw * 68 + 56 + wd] = 0u;
            else bufB[(rw - 64) * 68 + 56 + wd] = 0u;
        }
        if (wv < 7) {
            f32x4 c0 = {0.f,0.f,0.f,0.f}, c1 = {0.f,0.f,0.f,0.f};
            const int arow = (wv << 4) + (l64 & 15);
            const int kq   = (l64 >> 4) << 3;
            const int bn   = l64 & 15;
            const bool aok = arow < 100;
            #pragma unroll
            for (int kc = 0; kc < 4; ++kc) {
                const int kb = (kc << 5) + kq;
                f16x8 ah, al;
                if (aok) {
                    float av[8];
                    float4 xa = *(const float4*)&xg[arow*128 + kb];
                    float4 xb = *(const float4*)&xg[arow*128 + kb + 4];
                    av[0]=xa.x; av[1]=xa.y; av[2]=xa.z; av[3]=xa.w;
                    av[4]=xb.x; av[5]=xb.y; av[6]=xb.z; av[7]=xb.w;
                    split8(av, ah, al);
                } else {
                    #pragma unroll
                    for (int j = 0; j < 8; ++j) { ah[j] = (_Float16)0.f; al[j] = (_Float16)0.f; }
                }
                f16x8 b0h = __builtin_bit_cast(f16x8, *(const uint4*)(w1h + bn*64 + (kb>>1)));
                f16x8 b0l = __builtin_bit_cast(f16x8, *(const uint4*)(w1l + bn*64 + (kb>>1)));
                f16x8 b1h = __builtin_bit_cast(f16x8, *(const uint4*)(w1h + (bn+16)*64 + (kb>>1)));
                f16x8 b1l = __builtin_bit_cast(f16x8, *(const uint4*)(w1l + (bn+16)*64 + (kb>>1)));
                c0 = __builtin_amdgcn_mfma_f32_16x16x32_f16(ah, b0h, c0, 0, 0, 0);
                c0 = __builtin_amdgcn_mfma_f32_16x16x32_f16(al, b0h, c0, 0, 0, 0);
                c0 = __builtin_amdgcn_mfma_f32_16x16x32_f16(ah, b0l, c0, 0, 0, 0);
                c1 = __builtin_amdgcn_mfma_f32_16x16x32_f16(ah, b1h, c1, 0, 0, 0);
                c1 = __builtin_amdgcn_mfma_f32_16x16x32_f16(al, b1h, c1, 0, 0, 0);
                c1 = __builtin_amdgcn_mfma_f32_16x16x32_f16(ah, b1l, c1, 0, 0, 0);
            }
            const int r0 = (wv << 4) + ((l64 >> 4) << 2);
            float4 dv = *(const float4*)&dis[r0];
            packStore(bufA, c0, bn,      r0, dv);
            packStore(bufA, c1, bn + 16, r0, dv);
        }
        __syncthreads();

        // ---- AGG via MFMA (A from registers; reads buf) ----
        auto AGG = [&](const unsigned* buf, f32x4& fa, f32x4& fb, const float* Bp, bool wx) {
            if (wv < 7) {
                f32x4 a0 = {0.f,0.f,0.f,0.f}, a1 = {0.f,0.f,0.f,0.f};
                const unsigned* bb = buf + (l64 & 15) * 68 + ((l64 >> 4) << 2);
                #pragma unroll
                for (int p = 0; p < 2; ++p) {
                    const unsigned* bp = bb + p * 2176;
                    #pragma unroll
                    for (int ks = 0; ks < 4; ++ks) {
                        f16x8 b0 = __builtin_bit_cast(f16x8, *(const uint4*)(bp + ks*16));
                        f16x8 b1 = __builtin_bit_cast(f16x8, *(const uint4*)(bp + 16*68 + ks*16));
                        a0 = __builtin_amdgcn_mfma_f32_16x16x32_f16(afr[ks], b0, a0, 0, 0, 0);
                        a1 = __builtin_amdgcn_mfma_f32_16x16x32_f16(afr[ks], b1, a1, 0, 0, 0);
                    }
                }
                int n0 = l64 & 15, r0 = (wv << 4) + ((l64 >> 4) << 2);
                uint2 sh0 = *(const uint2*)(buf + n0 * 68 + (r0 >> 1));
                uint2 sl0 = *(const uint2*)(buf + 2176 + n0 * 68 + (r0 >> 1));
                uint2 sh1 = *(const uint2*)(buf + (16 + n0) * 68 + (r0 >> 1));
                uint2 sl1 = *(const uint2*)(buf + 2176 + (16 + n0) * 68 + (r0 >> 1));
                float4 dv = *(const float4*)&dis[r0];
                float bi0 = Bp[n0], bi1 = Bp[16 + n0];
                #pragma unroll
                for (int j = 0; j < 4; ++j) {
                    unsigned sft = (unsigned)((j & 1) * 16);
                    float sc0 = f16b(((j < 2) ? sh0.x : sh0.y) >> sft) +
                                f16b(((j < 2) ? sl0.x : sl0.y) >> sft);
                    float sc1 = f16b(((j < 2) ? sh1.x : sh1.y) >> sft) +
                                f16b(((j < 2) ? sl1.x : sl1.y) >> sft);
                    float d_ = (j == 0) ? dv.x : (j == 1) ? dv.y : (j == 2) ? dv.z : dv.w;
                    float v0 = ftanh(d_ * (a0[j] + sc0) + bi0);
                    float v1 = ftanh(d_ * (a1[j] + sc1) + bi1);
                    fa[j] = v0; fb[j] = v1;
                    if (wx) {
                        int row = r0 + j;
                        if (row < 100) { xrows[row*36 + n0] = v0; xrows[row*36 + 16 + n0] = v1; }
                    }
                }
            }
        };

        // ---- XW via MFMA: own-wave xrows -> other plane buffer ----
        auto XWm = [&](unsigned* bufDst, const unsigned* wh, const unsigned* wl) {
            if (wv < 7) {
                f32x4 c0 = {0.f,0.f,0.f,0.f}, c1 = {0.f,0.f,0.f,0.f};
                const int arow = (wv << 4) + (l64 & 15);
                const int kq   = (l64 >> 4) << 3;
                const int bn   = l64 & 15;
                f16x8 ah, al;
                if (arow < 100) {
                    float av[8];
                    float4 xa = *(const float4*)&xrows[arow*36 + kq];
                    float4 xb = *(const float4*)&xrows[arow*36 + kq + 4];
                    av[0]=xa.x; av[1]=xa.y; av[2]=xa.z; av[3]=xa.w;
                    av[4]=xb.x; av[5]=xb.y; av[6]=xb.z; av[7]=xb.w;
                    split8(av, ah, al);
                } else {
                    #pragma unroll
                    for (int j = 0; j < 8; ++j) { ah[j] = (_Float16)0.f; al[j] = (_Float16)0.f; }
                }
                f16x8 b0h = __builtin_bit_cast(f16x8, *(const uint4*)(wh + bn*16 + (kq>>1)));
                f16x8 b0l = __builtin_bit_cast(f16x8, *(const uint4*)(wl + bn*16 + (kq>>1)));
                f16x8 b1h = __builtin_bit_cast(f16x8, *(const uint4*)(wh + (bn+16)*16 + (kq>>1)));
                f16x8 b1l = __builtin_bit_cast(f16x8, *(const uint4*)(wl + (bn+16)*16 + (kq>>1)));
                c0 = __builtin_amdgcn_mfma_f32_16x16x32_f16(ah, b0h, c0, 0, 0, 0);
                c0 = __builtin_amdgcn_mfma_f32_16x16x32_f16(al, b0h, c0, 0, 0, 0);
                c0 = __builtin_amdgcn_mfma_f32_16x16x32_f16(ah, b0l, c0, 0, 0, 0);
                c1 = __builtin_amdgcn_mfma_f32_16x16x32_f16(ah, b1h, c1, 0, 0, 0);
                c1 = __builtin_amdgcn_mfma_f32_16x16x32_f16(al, b1h, c1, 0, 0, 0);
                c1 = __builtin_amdgcn_mfma_f32_16x16x32_f16(ah, b1l, c1, 0, 0, 0);
                const int r0 = (wv << 4) + ((l64 >> 4) << 2);
                float4 dv = *(const float4*)&dis[r0];
                packStore(bufDst, c0, bn,      r0, dv);
                packStore(bufDst, c1, bn + 16, r0, dv);
            }
        };

        f32x4 f1a, f1b, f2a, f2b, f3a, f3b;

        AGG(bufA, f1a, f1b, b1, true);
        XWm(bufB, wp + 4096, wp + 4608);     // W2
        __syncthreads();
        AGG(bufB, f2a, f2b, b2, true);
        XWm(bufA, wp + 5120, wp + 5632);     // W3
        __syncthreads();
        AGG(bufA, f3a, f3b, b3, false);

        // ---- L4 (32->1): t4[i] = dis_i * (x3 row . W4) via shfl reduce ----
        if (wv < 7) {
            float w4a = W4[l64 & 15], w4b = W4[16 + (l64 & 15)];
            int r0 = (wv << 4) + ((l64 >> 4) << 2);
            #pragma unroll
            for (int j = 0; j < 4; ++j) {
                float v = f3a[j] * w4a + f3b[j] * w4b;
                v += __shfl_xor(v, 1, 16); v += __shfl_xor(v, 2, 16);
                v += __shfl_xor(v, 4, 16); v += __shfl_xor(v, 8, 16);
                int row = r0 + j;
                if ((l64 & 15) == 0 && row < 100) t4[row] = v * dis[row];
            }
        }
        __syncthreads();

        // ---- pack t4 hi/lo; zero srank for rank phase ----
        if (tid < 64) {
            float a = (2*tid < 100) ? t4[2*tid] : 0.f;
            float bb_ = (2*tid+1 < 100) ? t4[2*tid+1] : 0.f;
            _Float16 ah = (_Float16)a, bh = (_Float16)bb_;
            t4h[tid] = (unsigned)__builtin_bit_cast(unsigned short, ah) |
                       ((unsigned)__builtin_bit_cast(unsigned short, bh) << 16);
            t4l[tid] = packh2(a - (float)ah, bb_ - (float)bh);
        }
        if (tid < 100) srank[tid] = 0;
        __syncthreads();

        // ---- L4 dot via MFMA (A from registers; only B-col 0 real) ----
        if (wv < 7) {
            f32x4 c = {0.f,0.f,0.f,0.f};
            const int kq2 = (l64 >> 4) << 2;
            const bool bz = (l64 & 15) == 0;
            #pragma unroll
            for (int ks = 0; ks < 4; ++ks) {
                f16x8 bh, bl;
                if (bz) {
                    bh = __builtin_bit_cast(f16x8, *(const uint4*)(t4h + ks*16 + kq2));
                    bl = __builtin_bit_cast(f16x8, *(const uint4*)(t4l + ks*16 + kq2));
                } else {
                    #pragma unroll
                    for (int j = 0; j < 8; ++j) { bh[j] = (_Float16)0.f; bl[j] = (_Float16)0.f; }
                }
                c = __builtin_amdgcn_mfma_f32_16x16x32_f16(afr[ks], bh, c, 0, 0, 0);
                c = __builtin_amdgcn_mfma_f32_16x16x32_f16(afr[ks], bl, c, 0, 0, 0);
            }
            if (bz) {
                int r0 = (wv << 4) + ((l64 >> 4) << 2);
                #pragma unroll
                for (int j = 0; j < 4; ++j) {
                    int row = r0 + j;
                    if (row < 100) sX4[row] = tanhf(dis[row] * (c[j] + t4[row]) + b4[0]);
                }
            }
        }
        __syncthreads();

        // ---- stable rank (value desc, index asc), wave-parallel ----
        if (tid < 500) {
            int i = tid / 5, seg = tid - i * 5;
            float vi = sX4[i];
            int c = 0, jb = seg * 20;
            #pragma unroll
            for (int jo = 0; jo < 20; ++jo) {
                int j = jb + jo;
                float vj = sX4[j];
                c += (vj > vi) || (vj == vi && j < i);
            }
            atomicAdd(&srank[i], c);
        }
        __syncthreads();

        // ---- gather top-30 rows into pooled[30][100] from frags ----
        if (wv < 7) {
            int n0 = l64 & 15, r0 = (wv << 4) + ((l64 >> 4) << 2);
            #pragma unroll
            for (int j = 0; j < 4; ++j) {
                int row = r0 + j;
                if (row < 100) {
                    int rk = srank[row];
                    if (rk < KTOP_C) {
                        float* pr = pooled + rk * 100;
                        pr[n0]      = f1a[j]; pr[16 + n0] = f1b[j];
                        pr[32 + n0] = f2a[j]; pr[48 + n0] = f2b[j];
                        pr[64 + n0] = f3a[j]; pr[80 + n0] = f3b[j];
                        if (n0 == 0) pr[96] = sX4[row];
                    }
                }
            }
        }
        __syncthreads();

        // ---- conv5 (97 -> 16) + ReLU + maxpool(2,2), fused: [16][15] ----
        if (tid < 240) {
            int l2 = tid >> 4, co = tid & 15;
            const float* wr = w5 + co * 97;
            float accs[2];
            #pragma unroll
            for (int t = 0; t < 2; ++t) {
                const float* pr = pooled + (2*l2 + t) * 100;
                float acc = b5[co];
                for (int c4 = 0; c4 < 96; c4 += 4) {
                    const float4 pv = *(const float4*)&pr[c4];
                    acc = fmaf(pv.x, wr[c4+0], fmaf(pv.y, wr[c4+1], fmaf(pv.z, wr[c4+2], fmaf(pv.w, wr[c4+3], acc))));
                }
                accs[t] = fmaf(pr[96], wr[96], acc);
            }
            sPb[co * 15 + l2] = fmaxf(fmaxf(accs[0], accs[1]), 0.f);
        }
        __syncthreads();

        // ---- conv6 (16 -> 32, k=5) + ReLU: [32][11] ----
        if (tid < 352) {
            int co = tid / 11, l = tid - co * 11;
            float acc = b6[co];
            for (int ci = 0; ci < 16; ++ci) {
                const float* wr = w6 + (co * 16 + ci) * 5;
                const float* pr = sPb + ci * 15 + l;
                acc = fmaf(wr[0], pr[0], fmaf(wr[1], pr[1], fmaf(wr[2], pr[2],
                      fmaf(wr[3], pr[3], fmaf(wr[4], pr[4], acc)))));
            }
            s6[co * 11 + l] = fmaxf(acc, 0.f);
        }
        __syncthreads();

        // ---- fc1 (352 -> 128) + ReLU ----
        {
            int j = tid & 127, part = tid >> 7;
            int ibeg = part * 88, iend = ibeg + 88;
            float acc = (part == 0) ? fb1[j] : 0.f;
            for (int i = ibeg; i < iend; ++i)
                acc = fmaf(s6[i], fw1[i * 128 + j], acc);
            sFc[part * 128 + j] = acc;
        }
        __syncthreads();
        if (tid < 128) {
            float v = sFc[tid] + sFc[128 + tid] + sFc[256 + tid] + sFc[384 + tid];
            sO1[tid] = fmaxf(v, 0.f);
        }
        __syncthreads();

        // ---- fc2 (128 -> 10) + log_softmax ----
        if (tid < 10) {
            float acc = fb2[tid];
            for (int k = 0; k < 128; ++k)
                acc = fmaf(sO1[k], fw2[k * 10 + tid], acc);
            sZ[tid] = acc;
        }
        __syncthreads();
        if (tid < 10) {
            float m = sZ[0];
            for (int c = 1; c < 10; ++c) m = fmaxf(m, sZ[c]);
            float se = 0.f;
            for (int c = 0; c < 10; ++c) se += expf(sZ[c] - m);
            out[g * 10 + tid] = sZ[tid] - m - logf(se);
        }
    }
}

extern "C" void kernel_launch(void* const* d_in, const int* in_sizes, int n_in,
                              void* d_out, int out_size, void* d_ws, size_t ws_size,
                              hipStream_t stream) {
    const float* x   = (const float*)d_in[0];
    const int*   ei  = (const int*)d_in[1];
    const int*   src = ei;
    const int*   dst = ei + N_EDGES_C;
    const float* W1 = (const float*)d_in[3];  const float* b1 = (const float*)d_in[4];
    const float* W2 = (const float*)d_in[5];  const float* b2 = (const float*)d_in[6];
    const float* W3 = (const float*)d_in[7];  const float* b3 = (const float*)d_in[8];
    const float* W4 = (const float*)d_in[9];  const float* b4 = (const float*)d_in[10];
    const float* w5 = (const float*)d_in[11]; const float* b5 = (const float*)d_in[12];
    const float* w6 = (const float*)d_in[13]; const float* b6 = (const float*)d_in[14];
    const float* fw1 = (const float*)d_in[15]; const float* fb1 = (const float*)d_in[16];
    const float* fw2 = (const float*)d_in[17]; const float* fb2 = (const float*)d_in[18];
    float* out = (float*)d_out;

    int* gcur = (int*)d_ws;
    unsigned short* slots = (unsigned short*)((char*)d_ws + 4096);
    unsigned* wpp = (unsigned*)((char*)d_ws + 4096 + (size_t)N_GRAPHS_C * CAP * 2);

    hipMemsetAsync(gcur, 0, 4096, stream);

    bucket_kernel<<<NB_BUCKET + 1, 1024, 0, stream>>>(src, dst, gcur, slots,
                                                      W1, W2, W3, wpp);

    size_t smem = (size_t)SMEM_WORDS * sizeof(unsigned);  // 51,392 B -> 3 blocks/CU
    hipFuncSetAttribute((const void*)dgcnn_kernel,
                        hipFuncAttributeMaxDynamicSharedMemorySize, (int)smem);
    dgcnn_kernel<<<NB_MAIN, 512, smem, stream>>>(
        x, gcur, slots, wpp, b1, b2, b3, W4, b4,
        w5, b5, w6, b6, fw1, fb1, fw2, fb2, out);
}

// Round 20
// 104.084 us; speedup vs baseline: 3.3460x; 3.3460x over previous
//
#include <hip/hip_runtime.h>

#define N_GRAPHS_C 1000
#define NPG_C      100
#define N_EDGES_C  3200000
#define KTOP_C     30
#define CAP        4096      // per-graph edge-slot capacity (mean 3200, sigma ~57)
#define NB_BUCKET  391       // edge blocks; block NB_BUCKET does wprep

typedef _Float16 f16x8 __attribute__((ext_vector_type(8)));
typedef float    f32x4 __attribute__((ext_vector_type(4)));

__device__ __forceinline__ unsigned packh2(float x, float y) {
    _Float16 hx = (_Float16)x, hy = (_Float16)y;
    return (unsigned)__builtin_bit_cast(unsigned short, hx) |
           ((unsigned)__builtin_bit_cast(unsigned short, hy) << 16);
}

__device__ __forceinline__ float f16b(unsigned v) {
    return (float)__builtin_bit_cast(_Float16, (unsigned short)v);
}

__device__ __forceinline__ float ftanh(float x) {
    float e = __expf(2.0f * x);
    return 1.0f - 2.0f * __builtin_amdgcn_rcpf(e + 1.0f);
}

__device__ __forceinline__ void split8(const float* v, f16x8& h, f16x8& l) {
    #pragma unroll
    for (int j = 0; j < 8; ++j) {
        _Float16 hh = (_Float16)v[j];
        h[j] = hh;
        l[j] = (_Float16)(v[j] - (float)hh);
    }
}

// ---------------- workspace layout (bytes) ----------------
// [0, 4096)                 : gcur  int[1024]  (memset to 0)
// [4096, 8196096)           : slots u16[1000*4096]  packed edges (d<<7 | s)
// [8196096, +24576)         : wp — f16 hi/lo planes of W1/W2/W3

__global__ __launch_bounds__(1024)
void bucket_kernel(const int* __restrict__ src, const int* __restrict__ dst,
                   int* __restrict__ gcur, unsigned short* __restrict__ slots,
                   const float* __restrict__ W1, const float* __restrict__ W2,
                   const float* __restrict__ W3, unsigned* __restrict__ wp) {
    const int tid = threadIdx.x;
    if (blockIdx.x == NB_BUCKET) {
        for (int w = tid; w < 2048; w += 1024) {
            int n = w >> 6, kp = w & 63, k = kp * 2;
            float a = W1[k*32 + n], b = W1[(k+1)*32 + n];
            _Float16 ah = (_Float16)a, bh = (_Float16)b;
            wp[w]        = (unsigned)__builtin_bit_cast(unsigned short, ah) |
                           ((unsigned)__builtin_bit_cast(unsigned short, bh) << 16);
            wp[2048 + w] = packh2(a - (float)ah, b - (float)bh);
        }
        for (int w = tid; w < 512; w += 1024) {
            int n = w >> 4, kp = w & 15, k = kp * 2;
            float a = W2[k*32 + n], b = W2[(k+1)*32 + n];
            _Float16 ah = (_Float16)a, bh = (_Float16)b;
            wp[4096 + w] = (unsigned)__builtin_bit_cast(unsigned short, ah) |
                           ((unsigned)__builtin_bit_cast(unsigned short, bh) << 16);
            wp[4608 + w] = packh2(a - (float)ah, b - (float)bh);
            float a3 = W3[k*32 + n], b3v = W3[(k+1)*32 + n];
            _Float16 a3h = (_Float16)a3, b3h = (_Float16)b3v;
            wp[5120 + w] = (unsigned)__builtin_bit_cast(unsigned short, a3h) |
                           ((unsigned)__builtin_bit_cast(unsigned short, b3h) << 16);
            wp[5632 + w] = packh2(a3 - (float)a3h, b3v - (float)b3h);
        }
        return;
    }

    __shared__ int hist[N_GRAPHS_C];
    const int base = blockIdx.x * 8192;
    for (int i = tid; i < N_GRAPHS_C; i += 1024) hist[i] = 0;
    __syncthreads();

    int g[8]; unsigned short pk[8]; bool v[8];
    #pragma unroll
    for (int k = 0; k < 8; ++k) {
        int e = base + tid + k * 1024;
        v[k] = false;
        if (e < N_EDGES_C) {
            int s = src[e], d = dst[e];
            if (s != d) {
                int gg = s / NPG_C;
                g[k] = gg;
                pk[k] = (unsigned short)(((d - gg * NPG_C) << 7) | (s - gg * NPG_C));
                v[k] = true;
                atomicAdd(&hist[gg], 1);
            }
        }
    }
    __syncthreads();
    for (int i = tid; i < N_GRAPHS_C; i += 1024) {
        int c = hist[i];
        hist[i] = atomicAdd(&gcur[i], c);
    }
    __syncthreads();
    #pragma unroll
    for (int k = 0; k < 8; ++k) {
        if (v[k]) {
            int pos = atomicAdd(&hist[g[k]], 1);
            if (pos < CAP) slots[g[k] * CAP + pos] = pk[k];
        }
    }
}

// ---------------- main per-graph kernel (r16 layout) ----------------
// LDS (u32 word offsets), total 12848 words = 51,392 B -> 3 blocks/CU:
//  bufA [0,4352)  bufB [4352,8704)  xrows/pooled [8704,12304)
//  dis [12304,12416)  t4 [12416,12520)  t4h [12520,12584)  t4l [12584,12648)
//  sX4 [12648,12748)  srank [12748,12848)
//  tail bufs sPb/s6/sO1/sFc/sZ (1248 f32) alias bufA (dead after AGG3)
#define SMEM_WORDS 12848

extern "C" __global__ __launch_bounds__(512, 6)
void dgcnn_kernel(const float* __restrict__ x,
                  const int* __restrict__ gcur, const unsigned short* __restrict__ slots,
                  const unsigned* __restrict__ wp,
                  const float* __restrict__ b1, const float* __restrict__ b2,
                  const float* __restrict__ b3,
                  const float* __restrict__ W4, const float* __restrict__ b4,
                  const float* __restrict__ w5, const float* __restrict__ b5,
                  const float* __restrict__ w6, const float* __restrict__ b6,
                  const float* __restrict__ fw1, const float* __restrict__ fb1,
                  const float* __restrict__ fw2, const float* __restrict__ fb2,
                  float* __restrict__ out)
{
    extern __shared__ unsigned smu[];
    unsigned* bufA = smu;                      // 4352
    unsigned* bufB = smu + 4352;               // 4352
    float* xrows  = (float*)(smu + 8704);      // 3600, stride 36
    float* pooled = (float*)(smu + 8704);      // [30][100] aliases xrows (dead)
    float* dis = (float*)(smu + 12304);        // 112
    float* t4  = (float*)(smu + 12416);        // 104
    unsigned* t4h = smu + 12520;               // 64
    unsigned* t4l = smu + 12584;               // 64
    float* sX4 = (float*)(smu + 12648);        // 100
    int*   srank = (int*)(smu + 12748);        // 100
    float* sPb = (float*)smu;                  // 240  (tail aliases bufA)
    float* s6  = (float*)smu + 240;            // 352
    float* sO1 = (float*)smu + 592;            // 128
    float* sFc = (float*)smu + 720;            // 512
    float* sZ  = (float*)smu + 1232;           // 16

    const int tid = threadIdx.x;
    const int g   = blockIdx.x;
    const int l64 = tid & 63;
    const int wv  = tid >> 6;                  // 0..7

    const float* xg = x + (size_t)g * NPG_C * 128;
    const unsigned* w1h = wp;
    const unsigned* w1l = wp + 2048;

    // ---- P0: zero scatter area; dis pads; rowsum accumulator; t4h/t4l tails ----
    for (int idx = tid; idx < 2600; idx += 512) bufA[idx] = 0u;
    if (tid < 12) dis[100 + tid] = 0.f;
    if (tid < 100) srank[tid] = 0;
    if (tid >= 400 && tid < 416) {             // rows 112..127 of packed t4
        int w = 56 + (tid & 7);
        if (tid < 408) t4h[w] = 0u; else t4l[w] = 0u;
    }
    __syncthreads();

    // ---- P1: scatter u8 counts (u8[100][104], row stride 26 words) ----
    {
        int ec = gcur[g]; if (ec > CAP) ec = CAP;
        for (int k = tid; k < ec; k += 512) {
            unsigned e = slots[g * CAP + k];
            unsigned idx = (e >> 7) * 104 + (e & 127);
            atomicAdd(&bufA[idx >> 2], 1u << ((idx & 3) * 8));
        }
    }
    __syncthreads();

    // ---- P2: wave-parallel rowsums + cnt A-frags -> registers ----
    if (tid < 400) {
        int row = tid >> 2, part = tid & 3;
        int wb = part * 7, we = (part == 3) ? 26 : wb + 7;
        const unsigned* rw = bufA + row * 26;
        unsigned s = 0;
        for (int k = wb; k < we; ++k) {
            unsigned v = rw[k];
            s += (v & 0xffu) + ((v >> 8) & 0xffu) + ((v >> 16) & 0xffu) + (v >> 24);
        }
        atomicAdd(&srank[row], (int)s);
    }
    f16x8 afr[4];
    {
        const int arow = (wv << 4) + (l64 & 15);
        if (wv < 7 && arow < 100) {
            const unsigned* cb = bufA + arow * 26 + ((l64 >> 4) << 1);
            #pragma unroll
            for (int ks = 0; ks < 4; ++ks) {
                uint2 cw = *(const uint2*)(cb + ks * 8);
                #pragma unroll
                for (int j = 0; j < 4; ++j) {
                    afr[ks][j]     = (_Float16)(float)((cw.x >> (8*j)) & 255u);
                    afr[ks][4 + j] = (_Float16)(float)((cw.y >> (8*j)) & 255u);
                }
            }
        } else {
            #pragma unroll
            for (int ks = 0; ks < 4; ++ks)
                #pragma unroll
                for (int j = 0; j < 8; ++j) afr[ks][j] = (_Float16)0.f;
        }
    }
    __syncthreads();

    // ---- P3: dis = rsqrt(rowsum + 1) ----
    if (tid < 100) dis[tid] = rsqrtf((float)srank[tid] + 1.0f);
    __syncthreads();

    // ---- C-frag -> Td planes (target buffer) ----
    auto packStore = [&](unsigned* buf, f32x4 c, int n, int r0, float4 dv) {
        float v0 = c[0]*dv.x, v1 = c[1]*dv.y, v2 = c[2]*dv.z, v3 = c[3]*dv.w;
        _Float16 h0=(_Float16)v0, h1=(_Float16)v1, h2=(_Float16)v2, h3=(_Float16)v3;
        uint2 wh, wl;
        wh.x = (unsigned)__builtin_bit_cast(unsigned short,h0) |
               ((unsigned)__builtin_bit_cast(unsigned short,h1) << 16);
        wh.y = (unsigned)__builtin_bit_cast(unsigned short,h2) |
               ((unsigned)__builtin_bit_cast(unsigned short,h3) << 16);
        wl.x = packh2(v0-(float)h0, v1-(float)h1);
        wl.y = packh2(v2-(float)h2, v3-(float)h3);
        *(uint2*)&buf[n*68 + (r0>>1)] = wh;
        *(uint2*)&buf[2176 + n*68 + (r0>>1)] = wl;
    };

    // ---- P4: zero pad words in BOTH buffers; re-zero srank for rank phase;
    //      L1 = X@W1 MFMA -> bufA ----
    for (int idx = tid; idx < 1536; idx += 512) {
        int b = idx >> 9;
        int r = idx & 511;
        int rw = (b * 512 + r) / 12, wd = (b * 512 + r) % 12;
        if (rw < 64) bufA[rw * 68 + 56 + wd] = 0u; else bufB[(rw - 64) * 68 + 56 + wd] = 0u;
    }
    if (tid < 100) srank[tid] = 0;             // rowsums consumed at P3
    if (wv < 7) {
        f32x4 c0 = {0.f,0.f,0.f,0.f}, c1 = {0.f,0.f,0.f,0.f};
        const int arow = (wv << 4) + (l64 & 15);
        const int kq   = (l64 >> 4) << 3;
        const int bn   = l64 & 15;
        const bool aok = arow < 100;
        #pragma unroll
        for (int kc = 0; kc < 4; ++kc) {
            const int kb = (kc << 5) + kq;
            f16x8 ah, al;
            if (aok) {
                float av[8];
                float4 xa = *(const float4*)&xg[arow*128 + kb];
                float4 xb = *(const float4*)&xg[arow*128 + kb + 4];
                av[0]=xa.x; av[1]=xa.y; av[2]=xa.z; av[3]=xa.w;
                av[4]=xb.x; av[5]=xb.y; av[6]=xb.z; av[7]=xb.w;
                split8(av, ah, al);
            } else {
                #pragma unroll
                for (int j = 0; j < 8; ++j) { ah[j] = (_Float16)0.f; al[j] = (_Float16)0.f; }
            }
            f16x8 b0h = __builtin_bit_cast(f16x8, *(const uint4*)(w1h + bn*64 + (kb>>1)));
            f16x8 b0l = __builtin_bit_cast(f16x8, *(const uint4*)(w1l + bn*64 + (kb>>1)));
            f16x8 b1h = __builtin_bit_cast(f16x8, *(const uint4*)(w1h + (bn+16)*64 + (kb>>1)));
            f16x8 b1l = __builtin_bit_cast(f16x8, *(const uint4*)(w1l + (bn+16)*64 + (kb>>1)));
            c0 = __builtin_amdgcn_mfma_f32_16x16x32_f16(ah, b0h, c0, 0, 0, 0);
            c0 = __builtin_amdgcn_mfma_f32_16x16x32_f16(al, b0h, c0, 0, 0, 0);
            c0 = __builtin_amdgcn_mfma_f32_16x16x32_f16(ah, b0l, c0, 0, 0, 0);
            c1 = __builtin_amdgcn_mfma_f32_16x16x32_f16(ah, b1h, c1, 0, 0, 0);
            c1 = __builtin_amdgcn_mfma_f32_16x16x32_f16(al, b1h, c1, 0, 0, 0);
            c1 = __builtin_amdgcn_mfma_f32_16x16x32_f16(ah, b1l, c1, 0, 0, 0);
        }
        const int r0 = (wv << 4) + ((l64 >> 4) << 2);
        float4 dv = *(const float4*)&dis[r0];
        packStore(bufA, c0, bn,      r0, dv);
        packStore(bufA, c1, bn + 16, r0, dv);
    }
    __syncthreads();

    // ---- AGG via MFMA (A from registers; reads buf) ----
    auto AGG = [&](const unsigned* buf, f32x4& fa, f32x4& fb, const float* Bp, bool wx) {
        if (wv < 7) {
            f32x4 a0 = {0.f,0.f,0.f,0.f}, a1 = {0.f,0.f,0.f,0.f};
            const unsigned* bb = buf + (l64 & 15) * 68 + ((l64 >> 4) << 2);
            #pragma unroll
            for (int p = 0; p < 2; ++p) {
                const unsigned* bp = bb + p * 2176;
                #pragma unroll
                for (int ks = 0; ks < 4; ++ks) {
                    f16x8 b0 = __builtin_bit_cast(f16x8, *(const uint4*)(bp + ks*16));
                    f16x8 b1 = __builtin_bit_cast(f16x8, *(const uint4*)(bp + 16*68 + ks*16));
                    a0 = __builtin_amdgcn_mfma_f32_16x16x32_f16(afr[ks], b0, a0, 0, 0, 0);
                    a1 = __builtin_amdgcn_mfma_f32_16x16x32_f16(afr[ks], b1, a1, 0, 0, 0);
                }
            }
            int n0 = l64 & 15, r0 = (wv << 4) + ((l64 >> 4) << 2);
            uint2 sh0 = *(const uint2*)(buf + n0 * 68 + (r0 >> 1));
            uint2 sl0 = *(const uint2*)(buf + 2176 + n0 * 68 + (r0 >> 1));
            uint2 sh1 = *(const uint2*)(buf + (16 + n0) * 68 + (r0 >> 1));
            uint2 sl1 = *(const uint2*)(buf + 2176 + (16 + n0) * 68 + (r0 >> 1));
            float4 dv = *(const float4*)&dis[r0];
            float bi0 = Bp[n0], bi1 = Bp[16 + n0];
            #pragma unroll
            for (int j = 0; j < 4; ++j) {
                unsigned sft = (unsigned)((j & 1) * 16);
                float sc0 = f16b(((j < 2) ? sh0.x : sh0.y) >> sft) +
                            f16b(((j < 2) ? sl0.x : sl0.y) >> sft);
                float sc1 = f16b(((j < 2) ? sh1.x : sh1.y) >> sft) +
                            f16b(((j < 2) ? sl1.x : sl1.y) >> sft);
                float d_ = (j == 0) ? dv.x : (j == 1) ? dv.y : (j == 2) ? dv.z : dv.w;
                float v0 = ftanh(d_ * (a0[j] + sc0) + bi0);
                float v1 = ftanh(d_ * (a1[j] + sc1) + bi1);
                fa[j] = v0; fb[j] = v1;
                if (wx) {
                    int row = r0 + j;
                    if (row < 100) { xrows[row*36 + n0] = v0; xrows[row*36 + 16 + n0] = v1; }
                }
            }
        }
    };

    // ---- XW via MFMA: own-wave xrows -> other plane buffer ----
    auto XWm = [&](unsigned* bufDst, const unsigned* wh, const unsigned* wl) {
        if (wv < 7) {
            f32x4 c0 = {0.f,0.f,0.f,0.f}, c1 = {0.f,0.f,0.f,0.f};
            const int arow = (wv << 4) + (l64 & 15);
            const int kq   = (l64 >> 4) << 3;
            const int bn   = l64 & 15;
            f16x8 ah, al;
            if (arow < 100) {
                float av[8];
                float4 xa = *(const float4*)&xrows[arow*36 + kq];
                float4 xb = *(const float4*)&xrows[arow*36 + kq + 4];
                av[0]=xa.x; av[1]=xa.y; av[2]=xa.z; av[3]=xa.w;
                av[4]=xb.x; av[5]=xb.y; av[6]=xb.z; av[7]=xb.w;
                split8(av, ah, al);
            } else {
                #pragma unroll
                for (int j = 0; j < 8; ++j) { ah[j] = (_Float16)0.f; al[j] = (_Float16)0.f; }
            }
            f16x8 b0h = __builtin_bit_cast(f16x8, *(const uint4*)(wh + bn*16 + (kq>>1)));
            f16x8 b0l = __builtin_bit_cast(f16x8, *(const uint4*)(wl + bn*16 + (kq>>1)));
            f16x8 b1h = __builtin_bit_cast(f16x8, *(const uint4*)(wh + (bn+16)*16 + (kq>>1)));
            f16x8 b1l = __builtin_bit_cast(f16x8, *(const uint4*)(wl + (bn+16)*16 + (kq>>1)));
            c0 = __builtin_amdgcn_mfma_f32_16x16x32_f16(ah, b0h, c0, 0, 0, 0);
            c0 = __builtin_amdgcn_mfma_f32_16x16x32_f16(al, b0h, c0, 0, 0, 0);
            c0 = __builtin_amdgcn_mfma_f32_16x16x32_f16(ah, b0l, c0, 0, 0, 0);
            c1 = __builtin_amdgcn_mfma_f32_16x16x32_f16(ah, b1h, c1, 0, 0, 0);
            c1 = __builtin_amdgcn_mfma_f32_16x16x32_f16(al, b1h, c1, 0, 0, 0);
            c1 = __builtin_amdgcn_mfma_f32_16x16x32_f16(ah, b1l, c1, 0, 0, 0);
            const int r0 = (wv << 4) + ((l64 >> 4) << 2);
            float4 dv = *(const float4*)&dis[r0];
            packStore(bufDst, c0, bn,      r0, dv);
            packStore(bufDst, c1, bn + 16, r0, dv);
        }
    };

    f32x4 f1a, f1b, f2a, f2b, f3a, f3b;

    AGG(bufA, f1a, f1b, b1, true);
    XWm(bufB, wp + 4096, wp + 4608);     // W2; no barrier: own-wave xrows, other buf
    __syncthreads();
    AGG(bufB, f2a, f2b, b2, true);
    XWm(bufA, wp + 5120, wp + 5632);     // W3
    __syncthreads();
    AGG(bufA, f3a, f3b, b3, false);

    // ---- L4 (32->1): shfl reduce; f==0 writes t4 AND packed t4h/t4l inline ----
    if (wv < 7) {
        float w4a = W4[l64 & 15], w4b = W4[16 + (l64 & 15)];
        int r0 = (wv << 4) + ((l64 >> 4) << 2);
        float tv[4];
        #pragma unroll
        for (int j = 0; j < 4; ++j) {
            float v = f3a[j] * w4a + f3b[j] * w4b;
            v += __shfl_xor(v, 1, 16); v += __shfl_xor(v, 2, 16);
            v += __shfl_xor(v, 4, 16); v += __shfl_xor(v, 8, 16);
            int row = r0 + j;
            tv[j] = (row < 100) ? v * dis[row] : 0.f;
        }
        if ((l64 & 15) == 0) {
            #pragma unroll
            for (int j = 0; j < 4; ++j) { int row = r0 + j; if (row < 100) t4[row] = tv[j]; }
            _Float16 h0=(_Float16)tv[0], h1=(_Float16)tv[1];
            _Float16 h2=(_Float16)tv[2], h3=(_Float16)tv[3];
            uint2 wh, wl;
            wh.x = (unsigned)__builtin_bit_cast(unsigned short,h0) |
                   ((unsigned)__builtin_bit_cast(unsigned short,h1) << 16);
            wh.y = (unsigned)__builtin_bit_cast(unsigned short,h2) |
                   ((unsigned)__builtin_bit_cast(unsigned short,h3) << 16);
            wl.x = packh2(tv[0]-(float)h0, tv[1]-(float)h1);
            wl.y = packh2(tv[2]-(float)h2, tv[3]-(float)h3);
            *(uint2*)&t4h[r0 >> 1] = wh;
            *(uint2*)&t4l[r0 >> 1] = wl;
        }
    }
    __syncthreads();

    // ---- L4 dot via MFMA (A from registers; only B-col 0 real) ----
    if (wv < 7) {
        f32x4 c = {0.f,0.f,0.f,0.f};
        const int kq2 = (l64 >> 4) << 2;
        const bool bz = (l64 & 15) == 0;
        #pragma unroll
        for (int ks = 0; ks < 4; ++ks) {
            f16x8 bh, bl;
            if (bz) {
                bh = __builtin_bit_cast(f16x8, *(const uint4*)(t4h + ks*16 + kq2));
                bl = __builtin_bit_cast(f16x8, *(const uint4*)(t4l + ks*16 + kq2));
            } else {
                #pragma unroll
                for (int j = 0; j < 8; ++j) { bh[j] = (_Float16)0.f; bl[j] = (_Float16)0.f; }
            }
            c = __builtin_amdgcn_mfma_f32_16x16x32_f16(afr[ks], bh, c, 0, 0, 0);
            c = __builtin_amdgcn_mfma_f32_16x16x32_f16(afr[ks], bl, c, 0, 0, 0);
        }
        if (bz) {
            int r0 = (wv << 4) + ((l64 >> 4) << 2);
            #pragma unroll
            for (int j = 0; j < 4; ++j) {
                int row = r0 + j;
                if (row < 100) sX4[row] = tanhf(dis[row] * (c[j] + t4[row]) + b4[0]);
            }
        }
    }
    __syncthreads();

    // ---- stable rank (value desc, index asc), wave-parallel ----
    if (tid < 500) {
        int i = tid / 5, seg = tid - i * 5;
        float vi = sX4[i];
        int c = 0, jb = seg * 20;
        #pragma unroll
        for (int jo = 0; jo < 20; ++jo) {
            int j = jb + jo;
            float vj = sX4[j];
            c += (vj > vi) || (vj == vi && j < i);
        }
        atomicAdd(&srank[i], c);
    }
    __syncthreads();

    // ---- gather top-30 rows into pooled[30][100] from frags ----
    if (wv < 7) {
        int n0 = l64 & 15, r0 = (wv << 4) + ((l64 >> 4) << 2);
        #pragma unroll
        for (int j = 0; j < 4; ++j) {
            int row = r0 + j;
            if (row < 100) {
                int rk = srank[row];
                if (rk < KTOP_C) {
                    float* pr = pooled + rk * 100;
                    pr[n0]      = f1a[j]; pr[16 + n0] = f1b[j];
                    pr[32 + n0] = f2a[j]; pr[48 + n0] = f2b[j];
                    pr[64 + n0] = f3a[j]; pr[80 + n0] = f3b[j];
                    if (n0 == 0) pr[96] = sX4[row];
                }
            }
        }
    }
    __syncthreads();

    // ---- conv5 (97 -> 16) + ReLU + maxpool(2,2), fused: [16][15] ----
    if (tid < 240) {
        int l2 = tid >> 4, co = tid & 15;
        const float* wr = w5 + co * 97;
        float accs[2];
        #pragma unroll
        for (int t = 0; t < 2; ++t) {
            const float* pr = pooled + (2*l2 + t) * 100;
            float acc = b5[co];
            for (int c4 = 0; c4 < 96; c4 += 4) {
                const float4 pv = *(const float4*)&pr[c4];
                acc = fmaf(pv.x, wr[c4+0], fmaf(pv.y, wr[c4+1], fmaf(pv.z, wr[c4+2], fmaf(pv.w, wr[c4+3], acc))));
            }
            accs[t] = fmaf(pr[96], wr[96], acc);
        }
        sPb[co * 15 + l2] = fmaxf(fmaxf(accs[0], accs[1]), 0.f);
    }
    __syncthreads();

    // ---- conv6 (16 -> 32, k=5) + ReLU: [32][11] ----
    if (tid < 352) {
        int co = tid / 11, l = tid - co * 11;
        float acc = b6[co];
        for (int ci = 0; ci < 16; ++ci) {
            const float* wr = w6 + (co * 16 + ci) * 5;
            const float* pr = sPb + ci * 15 + l;
            acc = fmaf(wr[0], pr[0], fmaf(wr[1], pr[1], fmaf(wr[2], pr[2],
                  fmaf(wr[3], pr[3], fmaf(wr[4], pr[4], acc)))));
        }
        s6[co * 11 + l] = fmaxf(acc, 0.f);
    }
    __syncthreads();

    // ---- fc1 (352 -> 128) + ReLU ----
    {
        int j = tid & 127, part = tid >> 7;
        int ibeg = part * 88, iend = ibeg + 88;
        float acc = (part == 0) ? fb1[j] : 0.f;
        for (int i = ibeg; i < iend; ++i)
            acc = fmaf(s6[i], fw1[i * 128 + j], acc);
        sFc[part * 128 + j] = acc;
    }
    __syncthreads();
    if (tid < 128) {
        float v = sFc[tid] + sFc[128 + tid] + sFc[256 + tid] + sFc[384 + tid];
        sO1[tid] = fmaxf(v, 0.f);
    }
    __syncthreads();

    // ---- fc2 (128 -> 10) + log_softmax ----
    if (tid < 10) {
        float acc = fb2[tid];
        for (int k = 0; k < 128; ++k)
            acc = fmaf(sO1[k], fw2[k * 10 + tid], acc);
        sZ[tid] = acc;
    }
    __syncthreads();
    if (tid < 10) {
        float m = sZ[0];
        for (int c = 1; c < 10; ++c) m = fmaxf(m, sZ[c]);
        float se = 0.f;
        for (int c = 0; c < 10; ++c) se += expf(sZ[c] - m);
        out[g * 10 + tid] = sZ[tid] - m - logf(se);
    }
}

extern "C" void kernel_launch(void* const* d_in, const int* in_sizes, int n_in,
                              void* d_out, int out_size, void* d_ws, size_t ws_size,
                              hipStream_t stream) {
    const float* x   = (const float*)d_in[0];
    const int*   ei  = (const int*)d_in[1];
    const int*   src = ei;
    const int*   dst = ei + N_EDGES_C;
    const float* W1 = (const float*)d_in[3];  const float* b1 = (const float*)d_in[4];
    const float* W2 = (const float*)d_in[5];  const float* b2 = (const float*)d_in[6];
    const float* W3 = (const float*)d_in[7];  const float* b3 = (const float*)d_in[8];
    const float* W4 = (const float*)d_in[9];  const float* b4 = (const float*)d_in[10];
    const float* w5 = (const float*)d_in[11]; const float* b5 = (const float*)d_in[12];
    const float* w6 = (const float*)d_in[13]; const float* b6 = (const float*)d_in[14];
    const float* fw1 = (const float*)d_in[15]; const float* fb1 = (const float*)d_in[16];
    const float* fw2 = (const float*)d_in[17]; const float* fb2 = (const float*)d_in[18];
    float* out = (float*)d_out;

    int* gcur = (int*)d_ws;
    unsigned short* slots = (unsigned short*)((char*)d_ws + 4096);
    unsigned* wpp = (unsigned*)((char*)d_ws + 4096 + (size_t)N_GRAPHS_C * CAP * 2);

    hipMemsetAsync(gcur, 0, 4096, stream);

    bucket_kernel<<<NB_BUCKET + 1, 1024, 0, stream>>>(src, dst, gcur, slots,
                                                      W1, W2, W3, wpp);

    size_t smem = (size_t)SMEM_WORDS * sizeof(unsigned);  // 51,392 B -> 3 blocks/CU
    hipFuncSetAttribute((const void*)dgcnn_kernel,
                        hipFuncAttributeMaxDynamicSharedMemorySize, (int)smem);
    dgcnn_kernel<<<N_GRAPHS_C, 512, smem, stream>>>(
        x, gcur, slots, wpp, b1, b2, b3, W4, b4,
        w5, b5, w6, b6, fw1, fb1, fw2, fb2, out);
}

// Round 21
// 100.172 us; speedup vs baseline: 3.4767x; 1.0391x over previous
//
#include <hip/hip_runtime.h>

#define N_GRAPHS_C 1000
#define NPG_C      100
#define N_EDGES_C  3200000
#define KTOP_C     30
#define CAP        4096      // per-graph edge-slot capacity (mean 3200, sigma ~57)
#define NB_BUCKET  391       // edge blocks; block NB_BUCKET does wprep

typedef _Float16 f16x8 __attribute__((ext_vector_type(8)));
typedef float    f32x4 __attribute__((ext_vector_type(4)));

__device__ __forceinline__ unsigned packh2(float x, float y) {
    _Float16 hx = (_Float16)x, hy = (_Float16)y;
    return (unsigned)__builtin_bit_cast(unsigned short, hx) |
           ((unsigned)__builtin_bit_cast(unsigned short, hy) << 16);
}

__device__ __forceinline__ float f16b(unsigned v) {
    return (float)__builtin_bit_cast(_Float16, (unsigned short)v);
}

__device__ __forceinline__ float ftanh(float x) {
    float e = __expf(2.0f * x);
    return 1.0f - 2.0f * __builtin_amdgcn_rcpf(e + 1.0f);
}

__device__ __forceinline__ void split8(const float* v, f16x8& h, f16x8& l) {
    #pragma unroll
    for (int j = 0; j < 8; ++j) {
        _Float16 hh = (_Float16)v[j];
        h[j] = hh;
        l[j] = (_Float16)(v[j] - (float)hh);
    }
}

// ---------------- workspace layout (bytes) ----------------
// [0, 4096)                 : gcur  int[1024]  (memset to 0)
// [4096, 8196096)           : slots u16[1000*4096]  packed edges (d<<7 | s)
// [8196096, +24576)         : wp — f16 hi/lo planes of W1/W2/W3

__global__ __launch_bounds__(1024)
void bucket_kernel(const int* __restrict__ src, const int* __restrict__ dst,
                   int* __restrict__ gcur, unsigned short* __restrict__ slots,
                   const float* __restrict__ W1, const float* __restrict__ W2,
                   const float* __restrict__ W3, unsigned* __restrict__ wp) {
    const int tid = threadIdx.x;
    if (blockIdx.x == NB_BUCKET) {
        for (int w = tid; w < 2048; w += 1024) {
            int n = w >> 6, kp = w & 63, k = kp * 2;
            float a = W1[k*32 + n], b = W1[(k+1)*32 + n];
            _Float16 ah = (_Float16)a, bh = (_Float16)b;
            wp[w]        = (unsigned)__builtin_bit_cast(unsigned short, ah) |
                           ((unsigned)__builtin_bit_cast(unsigned short, bh) << 16);
            wp[2048 + w] = packh2(a - (float)ah, b - (float)bh);
        }
        for (int w = tid; w < 512; w += 1024) {
            int n = w >> 4, kp = w & 15, k = kp * 2;
            float a = W2[k*32 + n], b = W2[(k+1)*32 + n];
            _Float16 ah = (_Float16)a, bh = (_Float16)b;
            wp[4096 + w] = (unsigned)__builtin_bit_cast(unsigned short, ah) |
                           ((unsigned)__builtin_bit_cast(unsigned short, bh) << 16);
            wp[4608 + w] = packh2(a - (float)ah, b - (float)bh);
            float a3 = W3[k*32 + n], b3v = W3[(k+1)*32 + n];
            _Float16 a3h = (_Float16)a3, b3h = (_Float16)b3v;
            wp[5120 + w] = (unsigned)__builtin_bit_cast(unsigned short, a3h) |
                           ((unsigned)__builtin_bit_cast(unsigned short, b3h) << 16);
            wp[5632 + w] = packh2(a3 - (float)a3h, b3v - (float)b3h);
        }
        return;
    }

    __shared__ int hist[N_GRAPHS_C];
    const int base = blockIdx.x * 8192;
    for (int i = tid; i < N_GRAPHS_C; i += 1024) hist[i] = 0;
    __syncthreads();

    int g[8]; unsigned short pk[8]; bool v[8];
    #pragma unroll
    for (int k = 0; k < 8; ++k) {
        int e = base + tid + k * 1024;
        v[k] = false;
        if (e < N_EDGES_C) {
            int s = src[e], d = dst[e];
            if (s != d) {
                int gg = s / NPG_C;
                g[k] = gg;
                pk[k] = (unsigned short)(((d - gg * NPG_C) << 7) | (s - gg * NPG_C));
                v[k] = true;
                atomicAdd(&hist[gg], 1);
            }
        }
    }
    __syncthreads();
    for (int i = tid; i < N_GRAPHS_C; i += 1024) {
        int c = hist[i];
        hist[i] = atomicAdd(&gcur[i], c);
    }
    __syncthreads();
    #pragma unroll
    for (int k = 0; k < 8; ++k) {
        if (v[k]) {
            int pos = atomicAdd(&hist[g[k]], 1);
            if (pos < CAP) slots[g[k] * CAP + pos] = pk[k];
        }
    }
}

// ---------------- main per-graph kernel: 256 threads, 4 waves x 2 tiles ----------------
// LDS (u32 word offsets), total 8496 words = 33,984 B -> 4 blocks/CU:
//  planes [0, 4352)       Td hi/lo planes ({hi,lo} x n(0..31) x 68 words)
//  xrows  [4352, 7952)    f32[100][36]; scatter u8[100][104] = first 2600 words
//                         (pre-AGG1); pooled[30][100] aliases after GCN
//  dis    [7952, 8064)    f32[112] (pads 0)
//  t4     [8064, 8168)    f32[104]
//  t4h    [8168, 8232)    t4l [8232, 8296)
//  sX4    [8296, 8396)    srank [8396, 8496)
//  tail bufs sPb/s6/sO1/sFc/sZ alias planes (dead after AGG3)
#define SMEM_WORDS 8496

extern "C" __global__ __launch_bounds__(256, 4)
void dgcnn_kernel(const float* __restrict__ x,
                  const int* __restrict__ gcur, const unsigned short* __restrict__ slots,
                  const unsigned* __restrict__ wp,
                  const float* __restrict__ b1, const float* __restrict__ b2,
                  const float* __restrict__ b3,
                  const float* __restrict__ W4, const float* __restrict__ b4,
                  const float* __restrict__ w5, const float* __restrict__ b5,
                  const float* __restrict__ w6, const float* __restrict__ b6,
                  const float* __restrict__ fw1, const float* __restrict__ fb1,
                  const float* __restrict__ fw2, const float* __restrict__ fb2,
                  float* __restrict__ out)
{
    extern __shared__ unsigned smu[];
    unsigned* planes = smu;                    // 4352
    unsigned* cnt    = smu + 4352;             // 2600 (scatter area, xrows region)
    float* xrows  = (float*)(smu + 4352);      // 3600, stride 36
    float* pooled = (float*)(smu + 4352);      // [30][100] aliases xrows (dead)
    float* dis = (float*)(smu + 7952);         // 112
    float* t4  = (float*)(smu + 8064);         // 104
    unsigned* t4h = smu + 8168;                // 64
    unsigned* t4l = smu + 8232;                // 64
    float* sX4 = (float*)(smu + 8296);         // 100
    int*   srank = (int*)(smu + 8396);         // 100
    float* sPb = (float*)smu;                  // 240  (tail aliases planes)
    float* s6  = (float*)smu + 240;            // 352
    float* sO1 = (float*)smu + 592;            // 128
    float* sFc = (float*)smu + 720;            // 256
    float* sZ  = (float*)smu + 976;            // 16

    const int tid = threadIdx.x;
    const int g   = blockIdx.x;
    const int l64 = tid & 63;
    const int wv  = tid >> 6;                  // 0..3

    const float* xg = x + (size_t)g * NPG_C * 128;
    const unsigned* w1h = wp;
    const unsigned* w1l = wp + 2048;

    // ---- P0: zero scatter area; dis pads; rowsum acc; t4h/t4l tails ----
    for (int idx = tid; idx < 2600; idx += 256) cnt[idx] = 0u;
    if (tid < 12) dis[100 + tid] = 0.f;
    if (tid < 100) srank[tid] = 0;
    if (tid >= 112 && tid < 120) t4h[56 + tid - 112] = 0u;
    if (tid >= 120 && tid < 128) t4l[56 + tid - 120] = 0u;
    __syncthreads();

    // ---- P1: scatter u8 counts (u8[100][104], row stride 26 words) ----
    {
        int ec = gcur[g]; if (ec > CAP) ec = CAP;
        for (int k = tid; k < ec; k += 256) {
            unsigned e = slots[g * CAP + k];
            unsigned idx = (e >> 7) * 104 + (e & 127);
            atomicAdd(&cnt[idx >> 2], 1u << ((idx & 3) * 8));
        }
    }
    __syncthreads();

    // ---- P2: rowsums (200 thr, 2-way) + cnt A-frags -> registers (2 tiles) ----
    if (tid < 200) {
        int row = tid >> 1, part = tid & 1;
        int wb = part * 13, we = wb + 13;
        const unsigned* rw = cnt + row * 26;
        unsigned s = 0;
        for (int k = wb; k < we; ++k) {
            unsigned v = rw[k];
            s += (v & 0xffu) + ((v >> 8) & 0xffu) + ((v >> 16) & 0xffu) + (v >> 24);
        }
        atomicAdd(&srank[row], (int)s);
    }
    f16x8 afr[8];   // [rt*4 + ks]
    #pragma unroll
    for (int rt = 0; rt < 2; ++rt) {
        const int ti = 2*wv + rt;
        const int arow = ti * 16 + (l64 & 15);
        if (ti < 7 && arow < 100) {
            const unsigned* cb = cnt + arow * 26 + ((l64 >> 4) << 1);
            #pragma unroll
            for (int ks = 0; ks < 4; ++ks) {
                uint2 cw = *(const uint2*)(cb + ks * 8);
                #pragma unroll
                for (int j = 0; j < 4; ++j) {
                    afr[rt*4+ks][j]     = (_Float16)(float)((cw.x >> (8*j)) & 255u);
                    afr[rt*4+ks][4 + j] = (_Float16)(float)((cw.y >> (8*j)) & 255u);
                }
            }
        } else {
            #pragma unroll
            for (int ks = 0; ks < 4; ++ks)
                #pragma unroll
                for (int j = 0; j < 8; ++j) afr[rt*4+ks][j] = (_Float16)0.f;
        }
    }
    __syncthreads();

    // ---- P3: dis = rsqrt(rowsum + 1) ----
    if (tid < 100) dis[tid] = rsqrtf((float)srank[tid] + 1.0f);
    __syncthreads();

    // ---- C-frag -> Td planes ----
    auto packStore = [&](f32x4 c, int n, int r0, float4 dv) {
        float v0 = c[0]*dv.x, v1 = c[1]*dv.y, v2 = c[2]*dv.z, v3 = c[3]*dv.w;
        _Float16 h0=(_Float16)v0, h1=(_Float16)v1, h2=(_Float16)v2, h3=(_Float16)v3;
        uint2 wh, wl;
        wh.x = (unsigned)__builtin_bit_cast(unsigned short,h0) |
               ((unsigned)__builtin_bit_cast(unsigned short,h1) << 16);
        wh.y = (unsigned)__builtin_bit_cast(unsigned short,h2) |
               ((unsigned)__builtin_bit_cast(unsigned short,h3) << 16);
        wl.x = packh2(v0-(float)h0, v1-(float)h1);
        wl.y = packh2(v2-(float)h2, v3-(float)h3);
        *(uint2*)&planes[n*68 + (r0>>1)] = wh;
        *(uint2*)&planes[2176 + n*68 + (r0>>1)] = wl;
    };

    // ---- P4: zero plane pad words; re-zero srank; L1 = X@W1 MFMA (2 tiles) ----
    for (int idx = tid; idx < 768; idx += 256) {
        int rw = idx / 12, wd = idx - rw * 12;
        planes[rw * 68 + 56 + wd] = 0u;
    }
    if (tid < 100) srank[tid] = 0;             // rowsums consumed at P3
    #pragma unroll
    for (int rt = 0; rt < 2; ++rt) {
        const int ti = 2*wv + rt;
        if (ti < 7) {
            f32x4 c0 = {0.f,0.f,0.f,0.f}, c1 = {0.f,0.f,0.f,0.f};
            const int arow = ti * 16 + (l64 & 15);
            const int kq   = (l64 >> 4) << 3;
            const int bn   = l64 & 15;
            const bool aok = arow < 100;
            #pragma unroll
            for (int kc = 0; kc < 4; ++kc) {
                const int kb = (kc << 5) + kq;
                f16x8 ah, al;
                if (aok) {
                    float av[8];
                    float4 xa = *(const float4*)&xg[arow*128 + kb];
                    float4 xb = *(const float4*)&xg[arow*128 + kb + 4];
                    av[0]=xa.x; av[1]=xa.y; av[2]=xa.z; av[3]=xa.w;
                    av[4]=xb.x; av[5]=xb.y; av[6]=xb.z; av[7]=xb.w;
                    split8(av, ah, al);
                } else {
                    #pragma unroll
                    for (int j = 0; j < 8; ++j) { ah[j] = (_Float16)0.f; al[j] = (_Float16)0.f; }
                }
                f16x8 b0h = __builtin_bit_cast(f16x8, *(const uint4*)(w1h + bn*64 + (kb>>1)));
                f16x8 b0l = __builtin_bit_cast(f16x8, *(const uint4*)(w1l + bn*64 + (kb>>1)));
                f16x8 b1h = __builtin_bit_cast(f16x8, *(const uint4*)(w1h + (bn+16)*64 + (kb>>1)));
                f16x8 b1l = __builtin_bit_cast(f16x8, *(const uint4*)(w1l + (bn+16)*64 + (kb>>1)));
                c0 = __builtin_amdgcn_mfma_f32_16x16x32_f16(ah, b0h, c0, 0, 0, 0);
                c0 = __builtin_amdgcn_mfma_f32_16x16x32_f16(al, b0h, c0, 0, 0, 0);
                c0 = __builtin_amdgcn_mfma_f32_16x16x32_f16(ah, b0l, c0, 0, 0, 0);
                c1 = __builtin_amdgcn_mfma_f32_16x16x32_f16(ah, b1h, c1, 0, 0, 0);
                c1 = __builtin_amdgcn_mfma_f32_16x16x32_f16(al, b1h, c1, 0, 0, 0);
                c1 = __builtin_amdgcn_mfma_f32_16x16x32_f16(ah, b1l, c1, 0, 0, 0);
            }
            const int r0 = ti * 16 + ((l64 >> 4) << 2);
            float4 dv = *(const float4*)&dis[r0];
            packStore(c0, bn,      r0, dv);
            packStore(c1, bn + 16, r0, dv);
        }
    }
    __syncthreads();

    // ---- AGG via MFMA (A from registers; reads planes; 2 tiles) ----
    auto AGG = [&](f32x4* fa, f32x4* fb, const float* Bp, bool wx) {
        #pragma unroll
        for (int rt = 0; rt < 2; ++rt) {
            const int ti = 2*wv + rt;
            if (ti < 7) {
                f32x4 a0 = {0.f,0.f,0.f,0.f}, a1 = {0.f,0.f,0.f,0.f};
                const unsigned* bb = planes + (l64 & 15) * 68 + ((l64 >> 4) << 2);
                #pragma unroll
                for (int p = 0; p < 2; ++p) {
                    const unsigned* bp = bb + p * 2176;
                    #pragma unroll
                    for (int ks = 0; ks < 4; ++ks) {
                        f16x8 b0 = __builtin_bit_cast(f16x8, *(const uint4*)(bp + ks*16));
                        f16x8 b1 = __builtin_bit_cast(f16x8, *(const uint4*)(bp + 16*68 + ks*16));
                        a0 = __builtin_amdgcn_mfma_f32_16x16x32_f16(afr[rt*4+ks], b0, a0, 0, 0, 0);
                        a1 = __builtin_amdgcn_mfma_f32_16x16x32_f16(afr[rt*4+ks], b1, a1, 0, 0, 0);
                    }
                }
                int n0 = l64 & 15, r0 = ti * 16 + ((l64 >> 4) << 2);
                uint2 sh0 = *(const uint2*)(planes + n0 * 68 + (r0 >> 1));
                uint2 sl0 = *(const uint2*)(planes + 2176 + n0 * 68 + (r0 >> 1));
                uint2 sh1 = *(const uint2*)(planes + (16 + n0) * 68 + (r0 >> 1));
                uint2 sl1 = *(const uint2*)(planes + 2176 + (16 + n0) * 68 + (r0 >> 1));
                float4 dv = *(const float4*)&dis[r0];
                float bi0 = Bp[n0], bi1 = Bp[16 + n0];
                #pragma unroll
                for (int j = 0; j < 4; ++j) {
                    unsigned sft = (unsigned)((j & 1) * 16);
                    float sc0 = f16b(((j < 2) ? sh0.x : sh0.y) >> sft) +
                                f16b(((j < 2) ? sl0.x : sl0.y) >> sft);
                    float sc1 = f16b(((j < 2) ? sh1.x : sh1.y) >> sft) +
                                f16b(((j < 2) ? sl1.x : sl1.y) >> sft);
                    float d_ = (j == 0) ? dv.x : (j == 1) ? dv.y : (j == 2) ? dv.z : dv.w;
                    float v0 = ftanh(d_ * (a0[j] + sc0) + bi0);
                    float v1 = ftanh(d_ * (a1[j] + sc1) + bi1);
                    fa[rt][j] = v0; fb[rt][j] = v1;
                    if (wx) {
                        int row = r0 + j;
                        if (row < 100) { xrows[row*36 + n0] = v0; xrows[row*36 + 16 + n0] = v1; }
                    }
                }
            }
        }
    };

    // ---- XW via MFMA: own-wave xrows rows -> planes (2 tiles) ----
    auto XWm = [&](const unsigned* wh, const unsigned* wl) {
        #pragma unroll
        for (int rt = 0; rt < 2; ++rt) {
            const int ti = 2*wv + rt;
            if (ti < 7) {
                f32x4 c0 = {0.f,0.f,0.f,0.f}, c1 = {0.f,0.f,0.f,0.f};
                const int arow = ti * 16 + (l64 & 15);
                const int kq   = (l64 >> 4) << 3;
                const int bn   = l64 & 15;
                f16x8 ah, al;
                if (arow < 100) {
                    float av[8];
                    float4 xa = *(const float4*)&xrows[arow*36 + kq];
                    float4 xb = *(const float4*)&xrows[arow*36 + kq + 4];
                    av[0]=xa.x; av[1]=xa.y; av[2]=xa.z; av[3]=xa.w;
                    av[4]=xb.x; av[5]=xb.y; av[6]=xb.z; av[7]=xb.w;
                    split8(av, ah, al);
                } else {
                    #pragma unroll
                    for (int j = 0; j < 8; ++j) { ah[j] = (_Float16)0.f; al[j] = (_Float16)0.f; }
                }
                f16x8 b0h = __builtin_bit_cast(f16x8, *(const uint4*)(wh + bn*16 + (kq>>1)));
                f16x8 b0l = __builtin_bit_cast(f16x8, *(const uint4*)(wl + bn*16 + (kq>>1)));
                f16x8 b1h = __builtin_bit_cast(f16x8, *(const uint4*)(wh + (bn+16)*16 + (kq>>1)));
                f16x8 b1l = __builtin_bit_cast(f16x8, *(const uint4*)(wl + (bn+16)*16 + (kq>>1)));
                c0 = __builtin_amdgcn_mfma_f32_16x16x32_f16(ah, b0h, c0, 0, 0, 0);
                c0 = __builtin_amdgcn_mfma_f32_16x16x32_f16(al, b0h, c0, 0, 0, 0);
                c0 = __builtin_amdgcn_mfma_f32_16x16x32_f16(ah, b0l, c0, 0, 0, 0);
                c1 = __builtin_amdgcn_mfma_f32_16x16x32_f16(ah, b1h, c1, 0, 0, 0);
                c1 = __builtin_amdgcn_mfma_f32_16x16x32_f16(al, b1h, c1, 0, 0, 0);
                c1 = __builtin_amdgcn_mfma_f32_16x16x32_f16(ah, b1l, c1, 0, 0, 0);
                const int r0 = ti * 16 + ((l64 >> 4) << 2);
                float4 dv = *(const float4*)&dis[r0];
                packStore(c0, bn,      r0, dv);
                packStore(c1, bn + 16, r0, dv);
            }
        }
    };

    f32x4 f1a[2], f1b[2], f2a[2], f2b[2], f3a[2], f3b[2];

    AGG(f1a, f1b, b1, true);
    __syncthreads();                 // planes reads done before XW overwrites
    XWm(wp + 4096, wp + 4608);       // W2
    __syncthreads();
    AGG(f2a, f2b, b2, true);
    __syncthreads();
    XWm(wp + 5120, wp + 5632);       // W3
    __syncthreads();
    AGG(f3a, f3b, b3, false);

    // ---- L4 (32->1): shfl reduce; (l64&15)==0 writes t4 + packed t4h/t4l ----
    {
        float w4a = W4[l64 & 15], w4b = W4[16 + (l64 & 15)];
        #pragma unroll
        for (int rt = 0; rt < 2; ++rt) {
            const int ti = 2*wv + rt;
            if (ti < 7) {
                int r0 = ti * 16 + ((l64 >> 4) << 2);
                float tv[4];
                #pragma unroll
                for (int j = 0; j < 4; ++j) {
                    float v = f3a[rt][j] * w4a + f3b[rt][j] * w4b;
                    v += __shfl_xor(v, 1, 16); v += __shfl_xor(v, 2, 16);
                    v += __shfl_xor(v, 4, 16); v += __shfl_xor(v, 8, 16);
                    int row = r0 + j;
                    tv[j] = (row < 100) ? v * dis[row] : 0.f;
                }
                if ((l64 & 15) == 0) {
                    #pragma unroll
                    for (int j = 0; j < 4; ++j) { int row = r0 + j; if (row < 100) t4[row] = tv[j]; }
                    _Float16 h0=(_Float16)tv[0], h1=(_Float16)tv[1];
                    _Float16 h2=(_Float16)tv[2], h3=(_Float16)tv[3];
                    uint2 wh, wl;
                    wh.x = (unsigned)__builtin_bit_cast(unsigned short,h0) |
                           ((unsigned)__builtin_bit_cast(unsigned short,h1) << 16);
                    wh.y = (unsigned)__builtin_bit_cast(unsigned short,h2) |
                           ((unsigned)__builtin_bit_cast(unsigned short,h3) << 16);
                    wl.x = packh2(tv[0]-(float)h0, tv[1]-(float)h1);
                    wl.y = packh2(tv[2]-(float)h2, tv[3]-(float)h3);
                    *(uint2*)&t4h[r0 >> 1] = wh;
                    *(uint2*)&t4l[r0 >> 1] = wl;
                }
            }
        }
    }
    __syncthreads();

    // ---- L4 dot via MFMA (A from registers; only B-col 0 real; 2 tiles) ----
    {
        const int kq2 = (l64 >> 4) << 2;
        const bool bz = (l64 & 15) == 0;
        #pragma unroll
        for (int rt = 0; rt < 2; ++rt) {
            const int ti = 2*wv + rt;
            if (ti < 7) {
                f32x4 c = {0.f,0.f,0.f,0.f};
                #pragma unroll
                for (int ks = 0; ks < 4; ++ks) {
                    f16x8 bh, bl;
                    if (bz) {
                        bh = __builtin_bit_cast(f16x8, *(const uint4*)(t4h + ks*16 + kq2));
                        bl = __builtin_bit_cast(f16x8, *(const uint4*)(t4l + ks*16 + kq2));
                    } else {
                        #pragma unroll
                        for (int j = 0; j < 8; ++j) { bh[j] = (_Float16)0.f; bl[j] = (_Float16)0.f; }
                    }
                    c = __builtin_amdgcn_mfma_f32_16x16x32_f16(afr[rt*4+ks], bh, c, 0, 0, 0);
                    c = __builtin_amdgcn_mfma_f32_16x16x32_f16(afr[rt*4+ks], bl, c, 0, 0, 0);
                }
                if (bz) {
                    int r0 = ti * 16 + ((l64 >> 4) << 2);
                    #pragma unroll
                    for (int j = 0; j < 4; ++j) {
                        int row = r0 + j;
                        if (row < 100) sX4[row] = tanhf(dis[row] * (c[j] + t4[row]) + b4[0]);
                    }
                }
            }
        }
    }
    __syncthreads();

    // ---- stable rank (value desc, index asc): 100 threads, serial 100 ----
    if (tid < 100) {
        float vi = sX4[tid];
        int c = 0;
        for (int j = 0; j < 100; ++j) {
            float vj = sX4[j];
            c += (vj > vi) || (vj == vi && j < tid);
        }
        srank[tid] = c;
    }
    __syncthreads();

    // ---- gather top-30 rows into pooled[30][100] from frags ----
    {
        int n0 = l64 & 15;
        #pragma unroll
        for (int rt = 0; rt < 2; ++rt) {
            const int ti = 2*wv + rt;
            if (ti < 7) {
                int r0 = ti * 16 + ((l64 >> 4) << 2);
                #pragma unroll
                for (int j = 0; j < 4; ++j) {
                    int row = r0 + j;
                    if (row < 100) {
                        int rk = srank[row];
                        if (rk < KTOP_C) {
                            float* pr = pooled + rk * 100;
                            pr[n0]      = f1a[rt][j]; pr[16 + n0] = f1b[rt][j];
                            pr[32 + n0] = f2a[rt][j]; pr[48 + n0] = f2b[rt][j];
                            pr[64 + n0] = f3a[rt][j]; pr[80 + n0] = f3b[rt][j];
                            if (n0 == 0) pr[96] = sX4[row];
                        }
                    }
                }
            }
        }
    }
    __syncthreads();

    // ---- conv5 (97 -> 16) + ReLU + maxpool(2,2), fused: [16][15] ----
    if (tid < 240) {
        int l2 = tid >> 4, co = tid & 15;
        const float* wr = w5 + co * 97;
        float accs[2];
        #pragma unroll
        for (int t = 0; t < 2; ++t) {
            const float* pr = pooled + (2*l2 + t) * 100;
            float acc = b5[co];
            for (int c4 = 0; c4 < 96; c4 += 4) {
                const float4 pv = *(const float4*)&pr[c4];
                acc = fmaf(pv.x, wr[c4+0], fmaf(pv.y, wr[c4+1], fmaf(pv.z, wr[c4+2], fmaf(pv.w, wr[c4+3], acc))));
            }
            accs[t] = fmaf(pr[96], wr[96], acc);
        }
        sPb[co * 15 + l2] = fmaxf(fmaxf(accs[0], accs[1]), 0.f);
    }
    __syncthreads();

    // ---- conv6 (16 -> 32, k=5) + ReLU: [32][11], 2 outputs/thread ----
    for (int o = tid; o < 352; o += 256) {
        int co = o / 11, l = o - co * 11;
        float acc = b6[co];
        for (int ci = 0; ci < 16; ++ci) {
            const float* wr = w6 + (co * 16 + ci) * 5;
            const float* pr = sPb + ci * 15 + l;
            acc = fmaf(wr[0], pr[0], fmaf(wr[1], pr[1], fmaf(wr[2], pr[2],
                  fmaf(wr[3], pr[3], fmaf(wr[4], pr[4], acc)))));
        }
        s6[co * 11 + l] = fmaxf(acc, 0.f);
    }
    __syncthreads();

    // ---- fc1 (352 -> 128) + ReLU: 2 partitions of 176 ----
    {
        int j = tid & 127, part = tid >> 7;    // 0..1
        int ibeg = part * 176, iend = ibeg + 176;
        float acc = (part == 0) ? fb1[j] : 0.f;
        for (int i = ibeg; i < iend; ++i)
            acc = fmaf(s6[i], fw1[i * 128 + j], acc);
        sFc[part * 128 + j] = acc;
    }
    __syncthreads();
    if (tid < 128) {
        float v = sFc[tid] + sFc[128 + tid];
        sO1[tid] = fmaxf(v, 0.f);
    }
    __syncthreads();

    // ---- fc2 (128 -> 10) + log_softmax ----
    if (tid < 10) {
        float acc = fb2[tid];
        for (int k = 0; k < 128; ++k)
            acc = fmaf(sO1[k], fw2[k * 10 + tid], acc);
        sZ[tid] = acc;
    }
    __syncthreads();
    if (tid < 10) {
        float m = sZ[0];
        for (int c = 1; c < 10; ++c) m = fmaxf(m, sZ[c]);
        float se = 0.f;
        for (int c = 0; c < 10; ++c) se += expf(sZ[c] - m);
        out[g * 10 + tid] = sZ[tid] - m - logf(se);
    }
}

extern "C" void kernel_launch(void* const* d_in, const int* in_sizes, int n_in,
                              void* d_out, int out_size, void* d_ws, size_t ws_size,
                              hipStream_t stream) {
    const float* x   = (const float*)d_in[0];
    const int*   ei  = (const int*)d_in[1];
    const int*   src = ei;
    const int*   dst = ei + N_EDGES_C;
    const float* W1 = (const float*)d_in[3];  const float* b1 = (const float*)d_in[4];
    const float* W2 = (const float*)d_in[5];  const float* b2 = (const float*)d_in[6];
    const float* W3 = (const float*)d_in[7];  const float* b3 = (const float*)d_in[8];
    const float* W4 = (const float*)d_in[9];  const float* b4 = (const float*)d_in[10];
    const float* w5 = (const float*)d_in[11]; const float* b5 = (const float*)d_in[12];
    const float* w6 = (const float*)d_in[13]; const float* b6 = (const float*)d_in[14];
    const float* fw1 = (const float*)d_in[15]; const float* fb1 = (const float*)d_in[16];
    const float* fw2 = (const float*)d_in[17]; const float* fb2 = (const float*)d_in[18];
    float* out = (float*)d_out;

    int* gcur = (int*)d_ws;
    unsigned short* slots = (unsigned short*)((char*)d_ws + 4096);
    unsigned* wpp = (unsigned*)((char*)d_ws + 4096 + (size_t)N_GRAPHS_C * CAP * 2);

    hipMemsetAsync(gcur, 0, 4096, stream);

    bucket_kernel<<<NB_BUCKET + 1, 1024, 0, stream>>>(src, dst, gcur, slots,
                                                      W1, W2, W3, wpp);

    size_t smem = (size_t)SMEM_WORDS * sizeof(unsigned);  // 33,984 B -> 4 blocks/CU
    hipFuncSetAttribute((const void*)dgcnn_kernel,
                        hipFuncAttributeMaxDynamicSharedMemorySize, (int)smem);
    dgcnn_kernel<<<N_GRAPHS_C, 256, smem, stream>>>(
        x, gcur, slots, wpp, b1, b2, b3, W4, b4,
        w5, b5, w6, b6, fw1, fb1, fw2, fb2, out);
}

// Round 22
// 97.660 us; speedup vs baseline: 3.5662x; 1.0257x over previous
//
#include <hip/hip_runtime.h>

#define N_GRAPHS_C 1000
#define NPG_C      100
#define N_EDGES_C  3200000
#define KTOP_C     30
#define CAP        4096      // per-graph edge-slot capacity (mean 3200, sigma ~57)
#define NB_BUCKET  391       // edge blocks; block NB_BUCKET does wprep

typedef _Float16 f16x8 __attribute__((ext_vector_type(8)));
typedef float    f32x4 __attribute__((ext_vector_type(4)));

__device__ __forceinline__ unsigned packh2(float x, float y) {
    _Float16 hx = (_Float16)x, hy = (_Float16)y;
    return (unsigned)__builtin_bit_cast(unsigned short, hx) |
           ((unsigned)__builtin_bit_cast(unsigned short, hy) << 16);
}

__device__ __forceinline__ float f16b(unsigned v) {
    return (float)__builtin_bit_cast(_Float16, (unsigned short)v);
}

__device__ __forceinline__ float ftanh(float x) {
    float e = __expf(2.0f * x);
    return 1.0f - 2.0f * __builtin_amdgcn_rcpf(e + 1.0f);
}

__device__ __forceinline__ void split8(const float* v, f16x8& h, f16x8& l) {
    #pragma unroll
    for (int j = 0; j < 8; ++j) {
        _Float16 hh = (_Float16)v[j];
        h[j] = hh;
        l[j] = (_Float16)(v[j] - (float)hh);
    }
}

// ---------------- workspace layout (bytes) ----------------
// [0, 4096)                 : gcur  int[1024]  (memset to 0)
// [4096, 8196096)           : slots u16[1000*4096]  packed edges (d<<7 | s)
// [8196096, +24576)         : wp — f16 hi/lo planes of W1/W2/W3

__global__ __launch_bounds__(1024)
void bucket_kernel(const int* __restrict__ src, const int* __restrict__ dst,
                   int* __restrict__ gcur, unsigned short* __restrict__ slots,
                   const float* __restrict__ W1, const float* __restrict__ W2,
                   const float* __restrict__ W3, unsigned* __restrict__ wp) {
    const int tid = threadIdx.x;
    if (blockIdx.x == NB_BUCKET) {
        for (int w = tid; w < 2048; w += 1024) {
            int n = w >> 6, kp = w & 63, k = kp * 2;
            float a = W1[k*32 + n], b = W1[(k+1)*32 + n];
            _Float16 ah = (_Float16)a, bh = (_Float16)b;
            wp[w]        = (unsigned)__builtin_bit_cast(unsigned short, ah) |
                           ((unsigned)__builtin_bit_cast(unsigned short, bh) << 16);
            wp[2048 + w] = packh2(a - (float)ah, b - (float)bh);
        }
        for (int w = tid; w < 512; w += 1024) {
            int n = w >> 4, kp = w & 15, k = kp * 2;
            float a = W2[k*32 + n], b = W2[(k+1)*32 + n];
            _Float16 ah = (_Float16)a, bh = (_Float16)b;
            wp[4096 + w] = (unsigned)__builtin_bit_cast(unsigned short, ah) |
                           ((unsigned)__builtin_bit_cast(unsigned short, bh) << 16);
            wp[4608 + w] = packh2(a - (float)ah, b - (float)bh);
            float a3 = W3[k*32 + n], b3v = W3[(k+1)*32 + n];
            _Float16 a3h = (_Float16)a3, b3h = (_Float16)b3v;
            wp[5120 + w] = (unsigned)__builtin_bit_cast(unsigned short, a3h) |
                           ((unsigned)__builtin_bit_cast(unsigned short, b3h) << 16);
            wp[5632 + w] = packh2(a3 - (float)a3h, b3v - (float)b3h);
        }
        return;
    }

    __shared__ int hist[N_GRAPHS_C];
    const int base = blockIdx.x * 8192;
    for (int i = tid; i < N_GRAPHS_C; i += 1024) hist[i] = 0;
    __syncthreads();

    int g[8]; unsigned short pk[8]; bool v[8];
    #pragma unroll
    for (int k = 0; k < 8; ++k) {
        int e = base + tid + k * 1024;
        v[k] = false;
        if (e < N_EDGES_C) {
            int s = src[e], d = dst[e];
            if (s != d) {
                int gg = s / NPG_C;
                g[k] = gg;
                pk[k] = (unsigned short)(((d - gg * NPG_C) << 7) | (s - gg * NPG_C));
                v[k] = true;
                atomicAdd(&hist[gg], 1);
            }
        }
    }
    __syncthreads();
    for (int i = tid; i < N_GRAPHS_C; i += 1024) {
        int c = hist[i];
        hist[i] = atomicAdd(&gcur[i], c);
    }
    __syncthreads();
    #pragma unroll
    for (int k = 0; k < 8; ++k) {
        if (v[k]) {
            int pos = atomicAdd(&hist[g[k]], 1);
            if (pos < CAP) slots[g[k] * CAP + pos] = pk[k];
        }
    }
}

// ---------------- main per-graph kernel: 256 threads, 4 waves x 2 tiles ----------------
// LDS (u32 word offsets), total 8496 words = 33,984 B -> 4 blocks/CU:
//  planes [0, 4352)       Td hi/lo planes; after AGG3: pooled[30][100] at [0,3000)
//                         + tail bufs sPb/s6/sO1/sFc/sZ at [3008,4000)
//  xrows  [4352, 7952)    f32[100][36] (x1/x2 transient, x3 until gather);
//                         scatter u8[100][104] = first 2600 words (pre-L1)
//  dis    [7952, 8064)    f32[112] (pads 0)
//  t4     [8064, 8168)    f32[104]
//  t4h    [8168, 8232)    t4l [8232, 8296)
//  sX4    [8296, 8396)    srank [8396, 8496)
#define SMEM_WORDS 8496

extern "C" __global__ __launch_bounds__(256, 4)
void dgcnn_kernel(const float* __restrict__ x,
                  const int* __restrict__ gcur, const unsigned short* __restrict__ slots,
                  const unsigned* __restrict__ wp,
                  const float* __restrict__ b1, const float* __restrict__ b2,
                  const float* __restrict__ b3,
                  const float* __restrict__ W4, const float* __restrict__ b4,
                  const float* __restrict__ w5, const float* __restrict__ b5,
                  const float* __restrict__ w6, const float* __restrict__ b6,
                  const float* __restrict__ fw1, const float* __restrict__ fb1,
                  const float* __restrict__ fw2, const float* __restrict__ fb2,
                  float* __restrict__ out)
{
    extern __shared__ unsigned smu[];
    unsigned* planes = smu;                    // 4352
    unsigned* cnt    = smu + 4352;             // 2600 (scatter area, xrows region)
    float* xrows  = (float*)(smu + 4352);      // 3600, stride 36
    float* pooled = (float*)smu;               // [30][100] over dead planes
    float* dis = (float*)(smu + 7952);         // 112
    float* t4  = (float*)(smu + 8064);         // 104
    unsigned* t4h = smu + 8168;                // 64
    unsigned* t4l = smu + 8232;                // 64
    float* sX4 = (float*)(smu + 8296);         // 100
    int*   srank = (int*)(smu + 8396);         // 100
    float* sPb = (float*)smu + 3008;           // 240  (planes region, past pooled)
    float* s6  = (float*)smu + 3248;           // 352
    float* sO1 = (float*)smu + 3600;           // 128
    float* sFc = (float*)smu + 3728;           // 256
    float* sZ  = (float*)smu + 3984;           // 16

    const int tid = threadIdx.x;
    const int g   = blockIdx.x;
    const int l64 = tid & 63;
    const int wv  = tid >> 6;                  // 0..3

    const float* xg = x + (size_t)g * NPG_C * 128;
    const unsigned* w1h = wp;
    const unsigned* w1l = wp + 2048;

    // ---- P0: zero scatter area; dis pads; rowsum acc; t4h/t4l tails ----
    for (int idx = tid; idx < 2600; idx += 256) cnt[idx] = 0u;
    if (tid < 12) dis[100 + tid] = 0.f;
    if (tid < 100) srank[tid] = 0;
    if (tid >= 112 && tid < 120) t4h[56 + tid - 112] = 0u;
    if (tid >= 120 && tid < 128) t4l[56 + tid - 120] = 0u;
    __syncthreads();

    // ---- P1: scatter u8 counts (u8[100][104], row stride 26 words) ----
    {
        int ec = gcur[g]; if (ec > CAP) ec = CAP;
        for (int k = tid; k < ec; k += 256) {
            unsigned e = slots[g * CAP + k];
            unsigned idx = (e >> 7) * 104 + (e & 127);
            atomicAdd(&cnt[idx >> 2], 1u << ((idx & 3) * 8));
        }
    }
    __syncthreads();

    // ---- P2: rowsums (200 thr, 2-way) + cnt A-frags -> registers (2 tiles) ----
    if (tid < 200) {
        int row = tid >> 1, part = tid & 1;
        int wb = part * 13, we = wb + 13;
        const unsigned* rw = cnt + row * 26;
        unsigned s = 0;
        for (int k = wb; k < we; ++k) {
            unsigned v = rw[k];
            s += (v & 0xffu) + ((v >> 8) & 0xffu) + ((v >> 16) & 0xffu) + (v >> 24);
        }
        atomicAdd(&srank[row], (int)s);
    }
    f16x8 afr[8];   // [rt*4 + ks]
    #pragma unroll
    for (int rt = 0; rt < 2; ++rt) {
        const int ti = 2*wv + rt;
        const int arow = ti * 16 + (l64 & 15);
        if (ti < 7 && arow < 100) {
            const unsigned* cb = cnt + arow * 26 + ((l64 >> 4) << 1);
            #pragma unroll
            for (int ks = 0; ks < 4; ++ks) {
                uint2 cw = *(const uint2*)(cb + ks * 8);
                #pragma unroll
                for (int j = 0; j < 4; ++j) {
                    afr[rt*4+ks][j]     = (_Float16)(float)((cw.x >> (8*j)) & 255u);
                    afr[rt*4+ks][4 + j] = (_Float16)(float)((cw.y >> (8*j)) & 255u);
                }
            }
        } else {
            #pragma unroll
            for (int ks = 0; ks < 4; ++ks)
                #pragma unroll
                for (int j = 0; j < 8; ++j) afr[rt*4+ks][j] = (_Float16)0.f;
        }
    }
    __syncthreads();

    // ---- P3: dis = rsqrt(rowsum + 1) ----
    if (tid < 100) dis[tid] = rsqrtf((float)srank[tid] + 1.0f);
    __syncthreads();

    // ---- C-frag -> Td planes ----
    auto packStore = [&](f32x4 c, int n, int r0, float4 dv) {
        float v0 = c[0]*dv.x, v1 = c[1]*dv.y, v2 = c[2]*dv.z, v3 = c[3]*dv.w;
        _Float16 h0=(_Float16)v0, h1=(_Float16)v1, h2=(_Float16)v2, h3=(_Float16)v3;
        uint2 wh, wl;
        wh.x = (unsigned)__builtin_bit_cast(unsigned short,h0) |
               ((unsigned)__builtin_bit_cast(unsigned short,h1) << 16);
        wh.y = (unsigned)__builtin_bit_cast(unsigned short,h2) |
               ((unsigned)__builtin_bit_cast(unsigned short,h3) << 16);
        wl.x = packh2(v0-(float)h0, v1-(float)h1);
        wl.y = packh2(v2-(float)h2, v3-(float)h3);
        *(uint2*)&planes[n*68 + (r0>>1)] = wh;
        *(uint2*)&planes[2176 + n*68 + (r0>>1)] = wl;
    };

    // ---- P4: zero plane pad words; L1 = X@W1 MFMA (2 tiles) ----
    for (int idx = tid; idx < 768; idx += 256) {
        int rw = idx / 12, wd = idx - rw * 12;
        planes[rw * 68 + 56 + wd] = 0u;
    }
    #pragma unroll
    for (int rt = 0; rt < 2; ++rt) {
        const int ti = 2*wv + rt;
        if (ti < 7) {
            f32x4 c0 = {0.f,0.f,0.f,0.f}, c1 = {0.f,0.f,0.f,0.f};
            const int arow = ti * 16 + (l64 & 15);
            const int kq   = (l64 >> 4) << 3;
            const int bn   = l64 & 15;
            const bool aok = arow < 100;
            #pragma unroll
            for (int kc = 0; kc < 4; ++kc) {
                const int kb = (kc << 5) + kq;
                f16x8 ah, al;
                if (aok) {
                    float av[8];
                    float4 xa = *(const float4*)&xg[arow*128 + kb];
                    float4 xb = *(const float4*)&xg[arow*128 + kb + 4];
                    av[0]=xa.x; av[1]=xa.y; av[2]=xa.z; av[3]=xa.w;
                    av[4]=xb.x; av[5]=xb.y; av[6]=xb.z; av[7]=xb.w;
                    split8(av, ah, al);
                } else {
                    #pragma unroll
                    for (int j = 0; j < 8; ++j) { ah[j] = (_Float16)0.f; al[j] = (_Float16)0.f; }
                }
                f16x8 b0h = __builtin_bit_cast(f16x8, *(const uint4*)(w1h + bn*64 + (kb>>1)));
                f16x8 b0l = __builtin_bit_cast(f16x8, *(const uint4*)(w1l + bn*64 + (kb>>1)));
                f16x8 b1h = __builtin_bit_cast(f16x8, *(const uint4*)(w1h + (bn+16)*64 + (kb>>1)));
                f16x8 b1l = __builtin_bit_cast(f16x8, *(const uint4*)(w1l + (bn+16)*64 + (kb>>1)));
                c0 = __builtin_amdgcn_mfma_f32_16x16x32_f16(ah, b0h, c0, 0, 0, 0);
                c0 = __builtin_amdgcn_mfma_f32_16x16x32_f16(al, b0h, c0, 0, 0, 0);
                c0 = __builtin_amdgcn_mfma_f32_16x16x32_f16(ah, b0l, c0, 0, 0, 0);
                c1 = __builtin_amdgcn_mfma_f32_16x16x32_f16(ah, b1h, c1, 0, 0, 0);
                c1 = __builtin_amdgcn_mfma_f32_16x16x32_f16(al, b1h, c1, 0, 0, 0);
                c1 = __builtin_amdgcn_mfma_f32_16x16x32_f16(ah, b1l, c1, 0, 0, 0);
            }
            const int r0 = ti * 16 + ((l64 >> 4) << 2);
            float4 dv = *(const float4*)&dis[r0];
            packStore(c0, bn,      r0, dv);
            packStore(c1, bn + 16, r0, dv);
        }
    }
    __syncthreads();

    // ---- AGG via MFMA (A from registers; reads planes; 2 tiles) ----
    auto AGG = [&](f32x4* fa, f32x4* fb, const float* Bp, bool keep) {
        #pragma unroll
        for (int rt = 0; rt < 2; ++rt) {
            const int ti = 2*wv + rt;
            if (ti < 7) {
                f32x4 a0 = {0.f,0.f,0.f,0.f}, a1 = {0.f,0.f,0.f,0.f};
                const unsigned* bb = planes + (l64 & 15) * 68 + ((l64 >> 4) << 2);
                #pragma unroll
                for (int p = 0; p < 2; ++p) {
                    const unsigned* bp = bb + p * 2176;
                    #pragma unroll
                    for (int ks = 0; ks < 4; ++ks) {
                        f16x8 b0 = __builtin_bit_cast(f16x8, *(const uint4*)(bp + ks*16));
                        f16x8 b1 = __builtin_bit_cast(f16x8, *(const uint4*)(bp + 16*68 + ks*16));
                        a0 = __builtin_amdgcn_mfma_f32_16x16x32_f16(afr[rt*4+ks], b0, a0, 0, 0, 0);
                        a1 = __builtin_amdgcn_mfma_f32_16x16x32_f16(afr[rt*4+ks], b1, a1, 0, 0, 0);
                    }
                }
                int n0 = l64 & 15, r0 = ti * 16 + ((l64 >> 4) << 2);
                uint2 sh0 = *(const uint2*)(planes + n0 * 68 + (r0 >> 1));
                uint2 sl0 = *(const uint2*)(planes + 2176 + n0 * 68 + (r0 >> 1));
                uint2 sh1 = *(const uint2*)(planes + (16 + n0) * 68 + (r0 >> 1));
                uint2 sl1 = *(const uint2*)(planes + 2176 + (16 + n0) * 68 + (r0 >> 1));
                float4 dv = *(const float4*)&dis[r0];
                float bi0 = Bp[n0], bi1 = Bp[16 + n0];
                #pragma unroll
                for (int j = 0; j < 4; ++j) {
                    unsigned sft = (unsigned)((j & 1) * 16);
                    float sc0 = f16b(((j < 2) ? sh0.x : sh0.y) >> sft) +
                                f16b(((j < 2) ? sl0.x : sl0.y) >> sft);
                    float sc1 = f16b(((j < 2) ? sh1.x : sh1.y) >> sft) +
                                f16b(((j < 2) ? sl1.x : sl1.y) >> sft);
                    float d_ = (j == 0) ? dv.x : (j == 1) ? dv.y : (j == 2) ? dv.z : dv.w;
                    float v0 = ftanh(d_ * (a0[j] + sc0) + bi0);
                    float v1 = ftanh(d_ * (a1[j] + sc1) + bi1);
                    if (keep) { fa[rt][j] = v0; fb[rt][j] = v1; }
                    int row = r0 + j;
                    if (row < 100) { xrows[row*36 + n0] = v0; xrows[row*36 + 16 + n0] = v1; }
                }
            }
        }
    };

    // ---- XW via MFMA: own-wave xrows rows -> planes (2 tiles) ----
    auto XWm = [&](const unsigned* wh, const unsigned* wl) {
        #pragma unroll
        for (int rt = 0; rt < 2; ++rt) {
            const int ti = 2*wv + rt;
            if (ti < 7) {
                f32x4 c0 = {0.f,0.f,0.f,0.f}, c1 = {0.f,0.f,0.f,0.f};
                const int arow = ti * 16 + (l64 & 15);
                const int kq   = (l64 >> 4) << 3;
                const int bn   = l64 & 15;
                f16x8 ah, al;
                if (arow < 100) {
                    float av[8];
                    float4 xa = *(const float4*)&xrows[arow*36 + kq];
                    float4 xb = *(const float4*)&xrows[arow*36 + kq + 4];
                    av[0]=xa.x; av[1]=xa.y; av[2]=xa.z; av[3]=xa.w;
                    av[4]=xb.x; av[5]=xb.y; av[6]=xb.z; av[7]=xb.w;
                    split8(av, ah, al);
                } else {
                    #pragma unroll
                    for (int j = 0; j < 8; ++j) { ah[j] = (_Float16)0.f; al[j] = (_Float16)0.f; }
                }
                f16x8 b0h = __builtin_bit_cast(f16x8, *(const uint4*)(wh + bn*16 + (kq>>1)));
                f16x8 b0l = __builtin_bit_cast(f16x8, *(const uint4*)(wl + bn*16 + (kq>>1)));
                f16x8 b1h = __builtin_bit_cast(f16x8, *(const uint4*)(wh + (bn+16)*16 + (kq>>1)));
                f16x8 b1l = __builtin_bit_cast(f16x8, *(const uint4*)(wl + (bn+16)*16 + (kq>>1)));
                c0 = __builtin_amdgcn_mfma_f32_16x16x32_f16(ah, b0h, c0, 0, 0, 0);
                c0 = __builtin_amdgcn_mfma_f32_16x16x32_f16(al, b0h, c0, 0, 0, 0);
                c0 = __builtin_amdgcn_mfma_f32_16x16x32_f16(ah, b0l, c0, 0, 0, 0);
                c1 = __builtin_amdgcn_mfma_f32_16x16x32_f16(ah, b1h, c1, 0, 0, 0);
                c1 = __builtin_amdgcn_mfma_f32_16x16x32_f16(al, b1h, c1, 0, 0, 0);
                c1 = __builtin_amdgcn_mfma_f32_16x16x32_f16(ah, b1l, c1, 0, 0, 0);
                const int r0 = ti * 16 + ((l64 >> 4) << 2);
                float4 dv = *(const float4*)&dis[r0];
                packStore(c0, bn,      r0, dv);
                packStore(c1, bn + 16, r0, dv);
            }
        }
    };

    f32x4 f1a[2], f1b[2], f2a[2], f2b[2];

    AGG(f1a, f1b, b1, true);
    __syncthreads();                 // planes reads done before XW overwrites
    XWm(wp + 4096, wp + 4608);       // W2
    __syncthreads();
    AGG(f2a, f2b, b2, true);
    __syncthreads();
    XWm(wp + 5120, wp + 5632);       // W3
    __syncthreads();
    AGG(nullptr, nullptr, b3, false);   // x3 -> xrows only
    __syncthreads();

    // ---- L4 row-dot: t4[i] = dis_i * (x3 row . W4), 100 threads ----
    if (tid < 100) {
        const float* xr = &xrows[tid * 36];
        float acc = 0.f;
        #pragma unroll
        for (int k4 = 0; k4 < 32; k4 += 4) {
            float4 v = *(const float4*)&xr[k4];
            acc = fmaf(v.x, W4[k4+0], fmaf(v.y, W4[k4+1],
                  fmaf(v.z, W4[k4+2], fmaf(v.w, W4[k4+3], acc))));
        }
        t4[tid] = acc * dis[tid];
    }
    __syncthreads();

    // ---- pack t4 hi/lo ----
    if (tid < 64) {
        float a = (2*tid < 100) ? t4[2*tid] : 0.f;
        float b = (2*tid+1 < 100) ? t4[2*tid+1] : 0.f;
        _Float16 ah = (_Float16)a, bh = (_Float16)b;
        t4h[tid] = (unsigned)__builtin_bit_cast(unsigned short, ah) |
                   ((unsigned)__builtin_bit_cast(unsigned short, bh) << 16);
        t4l[tid] = packh2(a - (float)ah, b - (float)bh);
    }
    __syncthreads();

    // ---- L4 dot via MFMA (A from registers; only B-col 0 real; 2 tiles) ----
    {
        const int kq2 = (l64 >> 4) << 2;
        const bool bz = (l64 & 15) == 0;
        #pragma unroll
        for (int rt = 0; rt < 2; ++rt) {
            const int ti = 2*wv + rt;
            if (ti < 7) {
                f32x4 c = {0.f,0.f,0.f,0.f};
                #pragma unroll
                for (int ks = 0; ks < 4; ++ks) {
                    f16x8 bh, bl;
                    if (bz) {
                        bh = __builtin_bit_cast(f16x8, *(const uint4*)(t4h + ks*16 + kq2));
                        bl = __builtin_bit_cast(f16x8, *(const uint4*)(t4l + ks*16 + kq2));
                    } else {
                        #pragma unroll
                        for (int j = 0; j < 8; ++j) { bh[j] = (_Float16)0.f; bl[j] = (_Float16)0.f; }
                    }
                    c = __builtin_amdgcn_mfma_f32_16x16x32_f16(afr[rt*4+ks], bh, c, 0, 0, 0);
                    c = __builtin_amdgcn_mfma_f32_16x16x32_f16(afr[rt*4+ks], bl, c, 0, 0, 0);
                }
                if (bz) {
                    int r0 = ti * 16 + ((l64 >> 4) << 2);
                    #pragma unroll
                    for (int j = 0; j < 4; ++j) {
                        int row = r0 + j;
                        if (row < 100) sX4[row] = tanhf(dis[row] * (c[j] + t4[row]) + b4[0]);
                    }
                }
            }
        }
    }
    __syncthreads();

    // ---- stable rank (value desc, index asc): 100 threads, serial 100 ----
    if (tid < 100) {
        float vi = sX4[tid];
        int c = 0;
        for (int j = 0; j < 100; ++j) {
            float vj = sX4[j];
            c += (vj > vi) || (vj == vi && j < tid);
        }
        srank[tid] = c;
    }
    __syncthreads();

    // ---- gather top-30 rows into pooled (planes region) ----
    {
        int n0 = l64 & 15;
        #pragma unroll
        for (int rt = 0; rt < 2; ++rt) {
            const int ti = 2*wv + rt;
            if (ti < 7) {
                int r0 = ti * 16 + ((l64 >> 4) << 2);
                #pragma unroll
                for (int j = 0; j < 4; ++j) {
                    int row = r0 + j;
                    if (row < 100) {
                        int rk = srank[row];
                        if (rk < KTOP_C) {
                            float* pr = pooled + rk * 100;
                            pr[n0]      = f1a[rt][j]; pr[16 + n0] = f1b[rt][j];
                            pr[32 + n0] = f2a[rt][j]; pr[48 + n0] = f2b[rt][j];
                            pr[64 + n0] = xrows[row*36 + n0];
                            pr[80 + n0] = xrows[row*36 + 16 + n0];
                            if (n0 == 0) pr[96] = sX4[row];
                        }
                    }
                }
            }
        }
    }
    __syncthreads();

    // ---- conv5 (97 -> 16) + ReLU + maxpool(2,2), fused: [16][15] ----
    if (tid < 240) {
        int l2 = tid >> 4, co = tid & 15;
        const float* wr = w5 + co * 97;
        float accs[2];
        #pragma unroll
        for (int t = 0; t < 2; ++t) {
            const float* pr = pooled + (2*l2 + t) * 100;
            float acc = b5[co];
            for (int c4 = 0; c4 < 96; c4 += 4) {
                const float4 pv = *(const float4*)&pr[c4];
                acc = fmaf(pv.x, wr[c4+0], fmaf(pv.y, wr[c4+1], fmaf(pv.z, wr[c4+2], fmaf(pv.w, wr[c4+3], acc))));
            }
            accs[t] = fmaf(pr[96], wr[96], acc);
        }
        sPb[co * 15 + l2] = fmaxf(fmaxf(accs[0], accs[1]), 0.f);
    }
    __syncthreads();

    // ---- conv6 (16 -> 32, k=5) + ReLU: [32][11], 2 outputs/thread ----
    for (int o = tid; o < 352; o += 256) {
        int co = o / 11, l = o - co * 11;
        float acc = b6[co];
        for (int ci = 0; ci < 16; ++ci) {
            const float* wr = w6 + (co * 16 + ci) * 5;
            const float* pr = sPb + ci * 15 + l;
            acc = fmaf(wr[0], pr[0], fmaf(wr[1], pr[1], fmaf(wr[2], pr[2],
                  fmaf(wr[3], pr[3], fmaf(wr[4], pr[4], acc)))));
        }
        s6[co * 11 + l] = fmaxf(acc, 0.f);
    }
    __syncthreads();

    // ---- fc1 (352 -> 128) + ReLU: 2 partitions of 176 ----
    {
        int j = tid & 127, part = tid >> 7;    // 0..1
        int ibeg = part * 176, iend = ibeg + 176;
        float acc = (part == 0) ? fb1[j] : 0.f;
        for (int i = ibeg; i < iend; ++i)
            acc = fmaf(s6[i], fw1[i * 128 + j], acc);
        sFc[part * 128 + j] = acc;
    }
    __syncthreads();
    if (tid < 128) {
        float v = sFc[tid] + sFc[128 + tid];
        sO1[tid] = fmaxf(v, 0.f);
    }
    __syncthreads();

    // ---- fc2 (128 -> 10) + log_softmax ----
    if (tid < 10) {
        float acc = fb2[tid];
        for (int k = 0; k < 128; ++k)
            acc = fmaf(sO1[k], fw2[k * 10 + tid], acc);
        sZ[tid] = acc;
    }
    __syncthreads();
    if (tid < 10) {
        float m = sZ[0];
        for (int c = 1; c < 10; ++c) m = fmaxf(m, sZ[c]);
        float se = 0.f;
        for (int c = 0; c < 10; ++c) se += expf(sZ[c] - m);
        out[g * 10 + tid] = sZ[tid] - m - logf(se);
    }
}

extern "C" void kernel_launch(void* const* d_in, const int* in_sizes, int n_in,
                              void* d_out, int out_size, void* d_ws, size_t ws_size,
                              hipStream_t stream) {
    const float* x   = (const float*)d_in[0];
    const int*   ei  = (const int*)d_in[1];
    const int*   src = ei;
    const int*   dst = ei + N_EDGES_C;
    const float* W1 = (const float*)d_in[3];  const float* b1 = (const float*)d_in[4];
    const float* W2 = (const float*)d_in[5];  const float* b2 = (const float*)d_in[6];
    const float* W3 = (const float*)d_in[7];  const float* b3 = (const float*)d_in[8];
    const float* W4 = (const float*)d_in[9];  const float* b4 = (const float*)d_in[10];
    const float* w5 = (const float*)d_in[11]; const float* b5 = (const float*)d_in[12];
    const float* w6 = (const float*)d_in[13]; const float* b6 = (const float*)d_in[14];
    const float* fw1 = (const float*)d_in[15]; const float* fb1 = (const float*)d_in[16];
    const float* fw2 = (const float*)d_in[17]; const float* fb2 = (const float*)d_in[18];
    float* out = (float*)d_out;

    int* gcur = (int*)d_ws;
    unsigned short* slots = (unsigned short*)((char*)d_ws + 4096);
    unsigned* wpp = (unsigned*)((char*)d_ws + 4096 + (size_t)N_GRAPHS_C * CAP * 2);

    hipMemsetAsync(gcur, 0, 4096, stream);

    bucket_kernel<<<NB_BUCKET + 1, 1024, 0, stream>>>(src, dst, gcur, slots,
                                                      W1, W2, W3, wpp);

    size_t smem = (size_t)SMEM_WORDS * sizeof(unsigned);  // 33,984 B -> 4 blocks/CU
    hipFuncSetAttribute((const void*)dgcnn_kernel,
                        hipFuncAttributeMaxDynamicSharedMemorySize, (int)smem);
    dgcnn_kernel<<<N_GRAPHS_C, 256, smem, stream>>>(
        x, gcur, slots, wpp, b1, b2, b3, W4, b4,
        w5, b5, w6, b6, fw1, fb1, fw2, fb2, out);
}